// Round 13
// baseline (815.390 us; speedup 1.0000x reference)
//
#include <hip/hip_runtime.h>
#include <hip/hip_bf16.h>

typedef __bf16 bf16x8_t __attribute__((ext_vector_type(8)));
typedef __bf16 bf16x4_t __attribute__((ext_vector_type(4)));
typedef short s16x4_t  __attribute__((ext_vector_type(4)));
typedef float f32x4_t  __attribute__((ext_vector_type(4)));

#define NB 2
#define NS 2048
#define NHID 3584
#define NHEADS 16
#define NKVH 8
#define DH 256
#define WIN 1024

__device__ __forceinline__ float bf2f(ushort u) {
  union { unsigned v; float f; } x; x.v = ((unsigned)u) << 16; return x.f;
}
__device__ __forceinline__ ushort f2bf(float f) {
  unsigned x = __builtin_bit_cast(unsigned, f);
  unsigned r = (x + 0x7fffu + ((x >> 16) & 1u)) >> 16;
  return (ushort)r;
}

__device__ __forceinline__ void gload16(const void* g, void* l) {
  __builtin_amdgcn_global_load_lds((const __attribute__((address_space(1))) void*)g,
                                   (__attribute__((address_space(3))) void*)l, 16, 0, 0);
}

__device__ __forceinline__ f32x4_t mfma_pv(s16x4_t a, s16x4_t b, f32x4_t c) {
#if __has_builtin(__builtin_amdgcn_mfma_f32_16x16x16_bf16)
  return __builtin_amdgcn_mfma_f32_16x16x16_bf16(
      __builtin_bit_cast(bf16x4_t, a), __builtin_bit_cast(bf16x4_t, b), c, 0, 0, 0);
#else
  return __builtin_amdgcn_mfma_f32_16x16x16bf16_1k(a, b, c, 0, 0, 0);
#endif
}

// p = exp(50*tanh((s/16)/50)); x = s/800; bounded by e^50 (fixed-max softmax safe)
__device__ __forceinline__ float pexp(float s) {
  float e = __expf(fminf(s * 0.0025f, 80.f));
  float th = __fdividef(e - 1.f, e + 1.f);
  return __expf(50.f * th);
}

// ---------------- f32 -> bf16 elementwise convert (x4 vectorized) ---------
__global__ __launch_bounds__(256) void f32_to_bf16_kernel(const float* __restrict__ in,
                                                          ushort* __restrict__ out, int n4) {
  int i = (int)blockIdx.x * 256 + (int)threadIdx.x;
  if (i < n4) {
    float4 v = ((const float4*)in)[i];
    ushort4 o;
    o.x = f2bf(v.x); o.y = f2bf(v.y); o.z = f2bf(v.z); o.w = f2bf(v.w);
    ((ushort4*)out)[i] = o;
  }
}

// ------------- transpose+convert: f32 in[R][C] -> bf16 out[C][R] ----------
__global__ __launch_bounds__(256) void transpose_f32_bf16(const float* __restrict__ in,
                                                          ushort* __restrict__ out,
                                                          int R, int Cc) {
  __shared__ ushort tile[64][72];
  const int t = threadIdx.x;
  const int ct = Cc >> 6;
  const int by = blockIdx.x / ct;
  const int bx = blockIdx.x % ct;
  const int r0 = by << 6, c0 = bx << 6;
#pragma unroll
  for (int i = 0; i < 16; ++i) {
    int idx = i * 256 + t;
    int r = idx >> 6, c = idx & 63;
    tile[r][c] = f2bf(in[(size_t)(r0 + r) * Cc + c0 + c]);
  }
  __syncthreads();
#pragma unroll
  for (int i = 0; i < 16; ++i) {
    int idx = i * 256 + t;
    int rr = idx >> 6, cc = idx & 63;
    out[(size_t)(c0 + rr) * R + r0 + cc] = tile[cc][rr];
  }
}

// ============ 8-phase 256x256 GEMM: C = A[M][K] * Bt[N][K]^T ==============
#define GSYNC1 do { __builtin_amdgcn_s_barrier(); \
    asm volatile("s_waitcnt lgkmcnt(0)" ::: "memory"); \
    __builtin_amdgcn_sched_barrier(0); } while (0)
#define GSYNC2(st) do { \
    if (st) asm volatile("s_waitcnt vmcnt(2)" ::: "memory"); \
    else    asm volatile("s_waitcnt vmcnt(0)" ::: "memory"); \
    __builtin_amdgcn_sched_barrier(0); \
    __builtin_amdgcn_s_barrier(); } while (0)

// EPI=0: bf16 C[M][N]. EPI=2: f32 C. EPI=4: fused KV — K half -> kbuf rows;
// V half -> vtbuf in ATTN-TILED layout: elem(b,kvh, s, d) =
//   plane(b*8+kvh)*524288 + (s>>5)*8192 + (d>>4)*512 + ((s&31)>>2)*64 + (d&15)*4 + (s&3)
template <int EPI>
__global__ __launch_bounds__(512, 2) void gemm256(const ushort* __restrict__ A,
                                                  const ushort* __restrict__ Bt,
                                                  void* __restrict__ Cout,
                                                  int M, int N, int K) {
  __shared__ alignas(16) char lds[131072];
  const int t = threadIdx.x;
  const int lane = t & 63;
  const int wid = t >> 6;
  const int wm = wid >> 2;   // 0..1
  const int wn = wid & 3;    // 0..3
  const int g = lane >> 4;
  const int lr = lane & 15;
  const int lrow8 = lane >> 3;
  const int lp = (lane & 7) ^ lrow8;  // pre-swizzled staging chunk

  const int nbn = N >> 8;
  const int nwg = (int)gridDim.x;
  const int bid = (int)blockIdx.x;
  const int swz = (bid & 7) * (nwg >> 3) + (bid >> 3);
  const int bm = swz / nbn, bn = swz % nbn;
  const int m0 = bm << 8, n0 = bn << 8;

  f32x4_t acc[8][4] = {};
  const int T = K >> 6;

  auto stageA = [&](int q, int koff, int bufn) {
    int row = (q << 6) + (wid << 3) + lrow8;
    gload16(A + (size_t)(m0 + row) * K + koff + (lp << 3),
            lds + bufn * 32768 + (q << 13) + (wid << 10));
  };
  auto stageB = [&](int q, int koff, int bufn) {
    int row = (q << 6) + (wid << 3) + lrow8;
    gload16(Bt + (size_t)(n0 + row) * K + koff + (lp << 3),
            lds + 65536 + bufn * 32768 + (q << 13) + (wid << 10));
  };

  // prologue: tile 0 -> buf 0
#pragma unroll
  for (int q = 0; q < 4; ++q) { stageA(q, 0, 0); stageB(q, 0, 0); }
  asm volatile("s_waitcnt vmcnt(0)" ::: "memory");
  __builtin_amdgcn_s_barrier();

  for (int tt = 0; tt < T; ++tt) {
    const int bc = tt & 1;
    const int bnx = bc ^ 1;
    const bool st = (tt + 1 < T);
    const int kn = (tt + 1) << 6;
    const char* cA = lds + bc * 32768;
    const char* cB = lds + 65536 + bc * 32768;
    bf16x8_t af[4], bfv[4];

    auto ldA = [&](int i, int mh, int ks) {
      int row = (wm << 7) + (mh << 6) + (i << 4) + lr;
      af[i] = *(const bf16x8_t*)(cA + (row << 7) + (((ks << 6) + (g << 4)) ^ ((row & 7) << 4)));
    };
    auto ldB = [&](int j, int ks) {
      int row = (wn << 6) + (j << 4) + lr;
      bfv[j] = *(const bf16x8_t*)(cB + (row << 7) + (((ks << 6) + (g << 4)) ^ ((row & 7) << 4)));
    };

    // ---- phase 0: mh0, ks0 ----
#pragma unroll
    for (int i = 0; i < 4; ++i) ldA(i, 0, 0);
#pragma unroll
    for (int j = 0; j < 4; ++j) ldB(j, 0);
    if (st) { stageA(0, kn, bnx); stageA(2, kn, bnx); }
    GSYNC1;
    __builtin_amdgcn_s_setprio(1);
#pragma unroll
    for (int i = 0; i < 4; ++i)
#pragma unroll
      for (int j = 0; j < 4; ++j)
        acc[i][j] = __builtin_amdgcn_mfma_f32_16x16x32_bf16(af[i], bfv[j], acc[i][j], 0, 0, 0);
    __builtin_amdgcn_s_setprio(0);
    GSYNC2(st);

    // ---- phase 1: mh1, ks0 ----
#pragma unroll
    for (int i = 0; i < 4; ++i) ldA(i, 1, 0);
    if (st) { stageB(0, kn, bnx); stageB(1, kn, bnx); }
    GSYNC1;
    __builtin_amdgcn_s_setprio(1);
#pragma unroll
    for (int i = 0; i < 4; ++i)
#pragma unroll
      for (int j = 0; j < 4; ++j)
        acc[4 + i][j] = __builtin_amdgcn_mfma_f32_16x16x32_bf16(af[i], bfv[j], acc[4 + i][j], 0, 0, 0);
    __builtin_amdgcn_s_setprio(0);
    GSYNC2(st);

    // ---- phase 2: mh0, ks1 ----
#pragma unroll
    for (int i = 0; i < 4; ++i) ldA(i, 0, 1);
#pragma unroll
    for (int j = 0; j < 4; ++j) ldB(j, 1);
    if (st) { stageB(2, kn, bnx); stageB(3, kn, bnx); }
    GSYNC1;
    __builtin_amdgcn_s_setprio(1);
#pragma unroll
    for (int i = 0; i < 4; ++i)
#pragma unroll
      for (int j = 0; j < 4; ++j)
        acc[i][j] = __builtin_amdgcn_mfma_f32_16x16x32_bf16(af[i], bfv[j], acc[i][j], 0, 0, 0);
    __builtin_amdgcn_s_setprio(0);
    GSYNC2(st);

    // ---- phase 3: mh1, ks1 ----
#pragma unroll
    for (int i = 0; i < 4; ++i) ldA(i, 1, 1);
    if (st) { stageA(1, kn, bnx); stageA(3, kn, bnx); }
    GSYNC1;
    __builtin_amdgcn_s_setprio(1);
#pragma unroll
    for (int i = 0; i < 4; ++i)
#pragma unroll
      for (int j = 0; j < 4; ++j)
        acc[4 + i][j] = __builtin_amdgcn_mfma_f32_16x16x32_bf16(af[i], bfv[j], acc[4 + i][j], 0, 0, 0);
    __builtin_amdgcn_s_setprio(0);
    GSYNC2(st);
  }

  // ---- epilogue ----
  __syncthreads();
  const bool trstage = (EPI == 4) && (n0 >= 2048);
  if (trstage) {
#pragma unroll
    for (int i = 0; i < 8; ++i)
#pragma unroll
      for (int j = 0; j < 4; ++j) {
        int col = (wn << 6) + (j << 4) + lr;
#pragma unroll
        for (int r = 0; r < 4; ++r) {
          int row = (wm << 7) + (i << 4) + (g << 2) + r;
          *(ushort*)(lds + (col << 9) + ((row << 1) ^ ((col & 7) << 4))) = f2bf(acc[i][j][r]);
        }
      }
  } else {
#pragma unroll
    for (int i = 0; i < 8; ++i)
#pragma unroll
      for (int j = 0; j < 4; ++j) {
        int col = (wn << 6) + (j << 4) + lr;
#pragma unroll
        for (int r = 0; r < 4; ++r) {
          int row = (wm << 7) + (i << 4) + (g << 2) + r;
          *(ushort*)(lds + (row << 9) + ((col << 1) ^ ((row & 7) << 4))) = f2bf(acc[i][j][r]);
        }
      }
  }
  __syncthreads();

  if (EPI == 0) {
    ushort* C = (ushort*)Cout;
#pragma unroll
    for (int it = 0; it < 16; ++it) {
      int idx = it * 512 + t;
      int row = idx >> 5, ch = idx & 31;
      uint4 v = *(const uint4*)(lds + (row << 9) + ((ch << 4) ^ ((row & 7) << 4)));
      *(uint4*)(C + (size_t)(m0 + row) * N + n0 + (ch << 3)) = v;
    }
  } else if (EPI == 4) {
    ushort* C = (ushort*)Cout;
    if (n0 < 2048) {
#pragma unroll
      for (int it = 0; it < 16; ++it) {
        int idx = it * 512 + t;
        int row = idx >> 5, ch = idx & 31;
        uint4 v = *(const uint4*)(lds + (row << 9) + ((ch << 4) ^ ((row & 7) << 4)));
        *(uint4*)(C + (size_t)(m0 + row) * 2048 + n0 + (ch << 3)) = v;
      }
    } else {
      // V half -> tiled vtbuf. Fully linear store: elem = base + s*8.
      ushort* vC = C + (size_t)4096 * 2048;
      const int plane = (m0 >> 11) * NKVH + ((n0 - 2048) >> 8);
      ushort* dst = vC + (size_t)plane * ((size_t)NS * DH) + (size_t)((m0 & (NS - 1)) >> 5) * 8192;
#pragma unroll
      for (int it = 0; it < 16; ++it) {
        int s = it * 512 + t;
        int lr2 = s & 7, kq = (s >> 3) & 7, dt_l = (s >> 6) & 15, sb_l = s >> 10;
        int d0 = (dt_l << 4) + (lr2 << 1);   // lds col
        int r0 = (sb_l << 5) + (kq << 2);    // lds row (token)
        uint2 a = *(const uint2*)(lds + (d0 << 9) + ((r0 << 1) ^ ((d0 & 7) << 4)));
        uint2 b2 = *(const uint2*)(lds + ((d0 + 1) << 9) + ((r0 << 1) ^ (((d0 + 1) & 7) << 4)));
        uint4 v; v.x = a.x; v.y = a.y; v.z = b2.x; v.w = b2.y;
        *(uint4*)(dst + (size_t)s * 8) = v;
      }
    }
  } else {
    float* Cf = (float*)Cout;
#pragma unroll
    for (int it = 0; it < 32; ++it) {
      int idx = it * 512 + t;
      int row = idx >> 6, qd = idx & 63;
      ushort4 hv = *(const ushort4*)(lds + (row << 9) + ((qd << 3) ^ ((row & 7) << 4)));
      float4 fv;
      fv.x = bf2f(hv.x); fv.y = bf2f(hv.y); fv.z = bf2f(hv.z); fv.w = bf2f(hv.w);
      *(float4*)(Cf + (size_t)(m0 + row) * N + n0 + (qd << 2)) = fv;
    }
  }
}

// ---------------- RoPE in-place on bf16 [B*S][nheads*256], pairs (d,d+128) -
__global__ __launch_bounds__(256) void rope_kernel(ushort* __restrict__ buf,
                                                   const float* __restrict__ sint,
                                                   const float* __restrict__ cost,
                                                   int nheads) {
  int idx = (int)blockIdx.x * 256 + (int)threadIdx.x;
  int d = idx & 127;
  int h = (idx >> 7) % nheads;
  int tok = idx / (nheads << 7);
  int pos = tok & (NS - 1);
  float c = cost[pos * DH + d];
  float s = sint[pos * DH + d];
  size_t base = (size_t)tok * ((size_t)nheads * DH) + h * DH + d;
  float x1 = bf2f(buf[base]);
  float x2 = bf2f(buf[base + 128]);
  buf[base] = f2bf(x1 * c - x2 * s);
  buf[base + 128] = f2bf(x2 * c + x1 * s);
}

// ---------------- flash attention v5: K-only LDS + V-direct + balance ------
// grid 1024 (QBLK=64, 4 waves). Block decode: xcd=bid&7 pins plane (b,kvh) to
// an XCD (2 planes = 4MB K+V = its L2); consecutive idx pairs qb with 31-qb
// (per-pair work ~const) for CU-level balance at 4 blocks/CU residency.
// K: 32KB dbuf via gload16 (proven swizzle). V: DIRECT global->VGPR from the
// tiled vtbuf (lane's PV B-frag = 8 contiguous bytes; 512B/wave coalesced,
// L2-served). LDS halved -> 4 blocks/CU (launch_bounds(256,4)).
__global__ __launch_bounds__(256, 4) void attn_kernel(const ushort* __restrict__ q,
                                                      const ushort* __restrict__ k,
                                                      const ushort* __restrict__ vt,
                                                      ushort* __restrict__ ao) {
  __shared__ alignas(16) char lK[2][16384];
  const int bid = (int)blockIdx.x;
  const int xcd = bid & 7;
  const int idx = bid >> 3;            // [0,128)
  const int flip = idx & 1;
  const int h_lsb = (idx >> 1) & 1;
  const int plane_hi = (idx >> 2) & 1;
  const int qb_base = idx >> 3;        // [0,16)
  const int qb = flip ? 31 - qb_base : qb_base;
  const int plane = xcd + (plane_hi << 3);   // b*8+kvh in [0,16)
  const int b = plane >> 3;
  const int kvh = plane & 7;
  const int h = (kvh << 1) | h_lsb;
  const int qb0 = qb << 6;
  const int t = threadIdx.x;
  const int lane = t & 63;
  const int w = t >> 6;
  const int g = lane >> 4;
  const int lr = lane & 15;

  const int qrow = qb0 + (w << 4) + lr;
  bf16x8_t qf[8];
  const ushort* qbase = q + (size_t)(b * NS + qrow) * (NHEADS * DH) + h * DH;
#pragma unroll
  for (int ks = 0; ks < 8; ++ks)
    qf[ks] = *(const bf16x8_t*)(qbase + (ks << 5) + (g << 3));

  float l_r = 0.f;
  f32x4_t oacc[16] = {};

  const int qminw = qb0 + (w << 4);
  const int qmaxw = qminw + 15;
  int t_lo = qb0 - (WIN - 1);
  if (t_lo < 0) t_lo = 0;
  t_lo &= ~31;
  const int t_hi = qb0 + 63;
  const int nt = ((t_hi - t_lo) >> 5) + 1;

  const ushort* kgb = k + (size_t)(b * NS) * (NKVH * DH) + kvh * DH;
  const ushort* vgb = vt + (size_t)(b * NKVH + kvh) * ((size_t)NS * DH);  // tiled plane

  auto stageK = [&](int kt, int bi) {
    char* dk = lK[bi];
#pragma unroll
    for (int j = 0; j < 4; ++j) {
      int row = (w << 3) + (j << 1) + (lane >> 5);
      int ck = (lane & 31) ^ (row & 7);
      gload16(kgb + (size_t)(kt + row) * (NKVH * DH) + (ck << 3),
              dk + (((w << 3) + (j << 1)) << 9));
    }
  };

  int cur = 0;
  stageK(t_lo, 0);
  __syncthreads();

  for (int i = 0; i < nt; ++i) {
    const int kt = t_lo + (i << 5);
    if (i + 1 < nt) stageK(kt + 32, cur ^ 1);  // async prefetch into other buf
    const char* lk = lK[cur];
    const ushort* vtile = vgb + (size_t)(kt >> 5) * 8192;  // 32-key V tile (16KB)
#pragma unroll
    for (int sub = 0; sub < 2; ++sub) {
      const int key0 = kt + (sub << 4);
      if (key0 > qmaxw) continue;
      if (key0 + 15 < qminw - (WIN - 1)) continue;

      f32x4_t sacc = {};
      __builtin_amdgcn_s_setprio(1);
#pragma unroll
      for (int ks = 0; ks < 8; ++ks) {
        int row = (sub << 4) + lr;
        bf16x8_t kf = *(const bf16x8_t*)(lk + (((row << 9) + (ks << 6) + (g << 4)) ^ ((row & 7) << 4)));
        sacc = __builtin_amdgcn_mfma_f32_16x16x32_bf16(kf, qf[ks], sacc, 0, 0, 0);
      }
      __builtin_amdgcn_s_setprio(0);

      float pvv[4];
      const bool full = (key0 + 15 <= qminw) && (key0 >= qmaxw - (WIN - 1));
      if (full) {
#pragma unroll
        for (int r = 0; r < 4; ++r) { pvv[r] = pexp(sacc[r]); l_r += pvv[r]; }
      } else {
#pragma unroll
        for (int r = 0; r < 4; ++r) {
          int key = key0 + (g << 2) + r;
          bool ok = (key <= qrow) && (qrow - key < WIN);
          pvv[r] = ok ? pexp(sacc[r]) : 0.f;
          l_r += pvv[r];
        }
      }

      s16x4_t pa;
      pa[0] = (short)f2bf(pvv[0]);
      pa[1] = (short)f2bf(pvv[1]);
      pa[2] = (short)f2bf(pvv[2]);
      pa[3] = (short)f2bf(pvv[3]);

      // V direct from global (tiled): lane frag = 8B at
      // dt*512 + (sub*4+g)*64 + lr*4 elements within the tile.
      const int voff = (((sub << 2) + g) << 6) + (lr << 2);
      __builtin_amdgcn_s_setprio(1);
#pragma unroll
      for (int dt = 0; dt < 16; ++dt) {
        s16x4_t vf = *(const s16x4_t*)(vtile + (dt << 9) + voff);
        oacc[dt] = mfma_pv(pa, vf, oacc[dt]);
      }
      __builtin_amdgcn_s_setprio(0);
    }
    __syncthreads();  // drains K prefetch; all waves done reading lK[cur]
    cur ^= 1;
  }

  l_r += __shfl_xor(l_r, 16);
  l_r += __shfl_xor(l_r, 32);
  float dn[4];
#pragma unroll
  for (int r = 0; r < 4; ++r)
    dn[r] = 1.0f / __shfl(l_r, (g << 2) + r);

  const int orow0 = b * NS + qb0 + (w << 4) + (g << 2);
#pragma unroll
  for (int dt = 0; dt < 16; ++dt) {
    int col = h * DH + (dt << 4) + lr;
#pragma unroll
    for (int r = 0; r < 4; ++r) {
      ao[(size_t)(orow0 + r) * (NHEADS * DH) + col] = f2bf(oacc[dt][r] * dn[r]);
    }
  }
}

extern "C" void kernel_launch(void* const* d_in, const int* in_sizes, int n_in,
                              void* d_out, int out_size, void* d_ws, size_t ws_size,
                              hipStream_t stream) {
  const float* hs   = (const float*)d_in[0];
  const float* sint = (const float*)d_in[3];
  const float* cost = (const float*)d_in[4];
  const float* Wq = (const float*)d_in[6];
  const float* Wk = (const float*)d_in[7];
  const float* Wv = (const float*)d_in[8];
  const float* Wo = (const float*)d_in[9];

  char* ws = (char*)d_ws;
  size_t off = 0;
  auto alloc = [&](size_t bytes) {
    char* p = ws + off;
    off += (bytes + 255) & ~(size_t)255;
    return p;
  };
  ushort* hsb   = (ushort*)alloc((size_t)4096 * 3584 * 2);  // hs in bf16
  ushort* wT    = (ushort*)alloc((size_t)4096 * 3584 * 2);  // reused weight^T buffer
  ushort* qbuf  = (ushort*)alloc((size_t)4096 * 4096 * 2);
  ushort* kbuf  = (ushort*)alloc((size_t)4096 * 2048 * 2);  // MUST precede vtbuf
  ushort* vtbuf = (ushort*)alloc((size_t)4096 * 2048 * 2);  // = kbuf + 4096*2048 (tiled)
  ushort* aobuf = qbuf;  // alias: attn writes exactly the region only it reads
  if (off > ws_size) return;

  // hs f32 -> bf16
  f32_to_bf16_kernel<<<(4096 * 3584 / 4) / 256, 256, 0, stream>>>(hs, hsb, 4096 * 3584 / 4);

  // fused K+V projection: Bt = [WkT; WvT] stacked in wT
  transpose_f32_bf16<<<(3584 / 64) * (2048 / 64), 256, 0, stream>>>(Wk, wT, 3584, 2048);
  transpose_f32_bf16<<<(3584 / 64) * (2048 / 64), 256, 0, stream>>>(Wv, wT + (size_t)2048 * 3584, 3584, 2048);
  gemm256<4><<<16 * 16, 512, 0, stream>>>(hsb, wT, kbuf, 4096, 4096, 3584);

  // Q projection
  transpose_f32_bf16<<<(3584 / 64) * (4096 / 64), 256, 0, stream>>>(Wq, wT, 3584, 4096);
  gemm256<0><<<16 * 16, 512, 0, stream>>>(hsb, wT, qbuf, 4096, 4096, 3584);

  // RoPE (q then k), in-place
  rope_kernel<<<(4096 * 16 * 128) / 256, 256, 0, stream>>>(qbuf, sint, cost, 16);
  rope_kernel<<<(4096 * 8 * 128) / 256, 256, 0, stream>>>(kbuf, sint, cost, 8);

  // attention: QBLK=64, K-only LDS, V-direct, balanced decode (ao aliases qbuf)
  attn_kernel<<<NB * NHEADS * (NS / 64), 256, 0, stream>>>(qbuf, kbuf, vtbuf, aobuf);

  // output projection, f32 out
  transpose_f32_bf16<<<(4096 / 64) * (3584 / 64), 256, 0, stream>>>(Wo, wT, 4096, 3584);
  gemm256<2><<<16 * 14, 512, 0, stream>>>(aobuf, wT, d_out, 4096, 3584, 4096);
}

// Round 14
// 587.282 us; speedup vs baseline: 1.3884x; 1.3884x over previous
//
#include <hip/hip_runtime.h>
#include <hip/hip_bf16.h>

typedef __bf16 bf16x8_t __attribute__((ext_vector_type(8)));
typedef __bf16 bf16x4_t __attribute__((ext_vector_type(4)));
typedef short s16x4_t  __attribute__((ext_vector_type(4)));
typedef float f32x4_t  __attribute__((ext_vector_type(4)));

#define NB 2
#define NS 2048
#define NHID 3584
#define NHEADS 16
#define NKVH 8
#define DH 256
#define WIN 1024

__device__ __forceinline__ float bf2f(ushort u) {
  union { unsigned v; float f; } x; x.v = ((unsigned)u) << 16; return x.f;
}
__device__ __forceinline__ ushort f2bf(float f) {
  unsigned x = __builtin_bit_cast(unsigned, f);
  unsigned r = (x + 0x7fffu + ((x >> 16) & 1u)) >> 16;
  return (ushort)r;
}

__device__ __forceinline__ void gload16(const void* g, void* l) {
  __builtin_amdgcn_global_load_lds((const __attribute__((address_space(1))) void*)g,
                                   (__attribute__((address_space(3))) void*)l, 16, 0, 0);
}

__device__ __forceinline__ f32x4_t mfma_pv(s16x4_t a, s16x4_t b, f32x4_t c) {
#if __has_builtin(__builtin_amdgcn_mfma_f32_16x16x16_bf16)
  return __builtin_amdgcn_mfma_f32_16x16x16_bf16(
      __builtin_bit_cast(bf16x4_t, a), __builtin_bit_cast(bf16x4_t, b), c, 0, 0, 0);
#else
  return __builtin_amdgcn_mfma_f32_16x16x16bf16_1k(a, b, c, 0, 0, 0);
#endif
}

// p = exp(50*tanh((s/16)/50)); x = s/800; bounded by e^50 (fixed-max softmax safe)
__device__ __forceinline__ float pexp(float s) {
  float e = __expf(fminf(s * 0.0025f, 80.f));
  float th = __fdividef(e - 1.f, e + 1.f);
  return __expf(50.f * th);
}

// ---------------- f32 -> bf16 elementwise convert (x4 vectorized) ---------
__global__ __launch_bounds__(256) void f32_to_bf16_kernel(const float* __restrict__ in,
                                                          ushort* __restrict__ out, int n4) {
  int i = (int)blockIdx.x * 256 + (int)threadIdx.x;
  if (i < n4) {
    float4 v = ((const float4*)in)[i];
    ushort4 o;
    o.x = f2bf(v.x); o.y = f2bf(v.y); o.z = f2bf(v.z); o.w = f2bf(v.w);
    ((ushort4*)out)[i] = o;
  }
}

// ------------- transpose+convert: f32 in[R][C] -> bf16 out[C][R] ----------
__global__ __launch_bounds__(256) void transpose_f32_bf16(const float* __restrict__ in,
                                                          ushort* __restrict__ out,
                                                          int R, int Cc) {
  __shared__ ushort tile[64][72];
  const int t = threadIdx.x;
  const int ct = Cc >> 6;
  const int by = blockIdx.x / ct;
  const int bx = blockIdx.x % ct;
  const int r0 = by << 6, c0 = bx << 6;
#pragma unroll
  for (int i = 0; i < 16; ++i) {
    int idx = i * 256 + t;
    int r = idx >> 6, c = idx & 63;
    tile[r][c] = f2bf(in[(size_t)(r0 + r) * Cc + c0 + c]);
  }
  __syncthreads();
#pragma unroll
  for (int i = 0; i < 16; ++i) {
    int idx = i * 256 + t;
    int rr = idx >> 6, cc = idx & 63;
    out[(size_t)(c0 + rr) * R + r0 + cc] = tile[cc][rr];
  }
}

// ============ 8-phase 256x256 GEMM: C = A[M][K] * Bt[N][K]^T ==============
#define GSYNC1 do { __builtin_amdgcn_s_barrier(); \
    asm volatile("s_waitcnt lgkmcnt(0)" ::: "memory"); \
    __builtin_amdgcn_sched_barrier(0); } while (0)
#define GSYNC2(st) do { \
    if (st) asm volatile("s_waitcnt vmcnt(2)" ::: "memory"); \
    else    asm volatile("s_waitcnt vmcnt(0)" ::: "memory"); \
    __builtin_amdgcn_sched_barrier(0); \
    __builtin_amdgcn_s_barrier(); } while (0)

// EPI=1: bf16 C[M][N] + fused RoPE (tile N=256 = one head; pairs (d,d+128)
//        in-tile; sin/cos tables have duplicated halves so index [pos*256+d]).
// EPI=2: f32 C (no rope). EPI=5: fused KV — K half -> kbuf rows WITH RoPE;
// V half -> vtbuf ATTN-TILED (no rope): elem(b,kvh,s,d) =
//   plane*524288 + (s>>5)*8192 + (d>>4)*512 + ((s&31)>>2)*64 + (d&15)*4 + (s&3)
template <int EPI>
__global__ __launch_bounds__(512, 2) void gemm256(const ushort* __restrict__ A,
                                                  const ushort* __restrict__ Bt,
                                                  void* __restrict__ Cout,
                                                  const float* __restrict__ sinT,
                                                  const float* __restrict__ cosT,
                                                  int M, int N, int K) {
  __shared__ alignas(16) char lds[131072];
  const int t = threadIdx.x;
  const int lane = t & 63;
  const int wid = t >> 6;
  const int wm = wid >> 2;   // 0..1
  const int wn = wid & 3;    // 0..3
  const int g = lane >> 4;
  const int lr = lane & 15;
  const int lrow8 = lane >> 3;
  const int lp = (lane & 7) ^ lrow8;  // pre-swizzled staging chunk

  const int nbn = N >> 8;
  const int nwg = (int)gridDim.x;
  const int bid = (int)blockIdx.x;
  const int swz = (bid & 7) * (nwg >> 3) + (bid >> 3);
  const int bm = swz / nbn, bn = swz % nbn;
  const int m0 = bm << 8, n0 = bn << 8;

  f32x4_t acc[8][4] = {};
  const int T = K >> 6;

  auto stageA = [&](int q, int koff, int bufn) {
    int row = (q << 6) + (wid << 3) + lrow8;
    gload16(A + (size_t)(m0 + row) * K + koff + (lp << 3),
            lds + bufn * 32768 + (q << 13) + (wid << 10));
  };
  auto stageB = [&](int q, int koff, int bufn) {
    int row = (q << 6) + (wid << 3) + lrow8;
    gload16(Bt + (size_t)(n0 + row) * K + koff + (lp << 3),
            lds + 65536 + bufn * 32768 + (q << 13) + (wid << 10));
  };

  // prologue: tile 0 -> buf 0
#pragma unroll
  for (int q = 0; q < 4; ++q) { stageA(q, 0, 0); stageB(q, 0, 0); }
  asm volatile("s_waitcnt vmcnt(0)" ::: "memory");
  __builtin_amdgcn_s_barrier();

  for (int tt = 0; tt < T; ++tt) {
    const int bc = tt & 1;
    const int bnx = bc ^ 1;
    const bool st = (tt + 1 < T);
    const int kn = (tt + 1) << 6;
    const char* cA = lds + bc * 32768;
    const char* cB = lds + 65536 + bc * 32768;
    bf16x8_t af[4], bfv[4];

    auto ldA = [&](int i, int mh, int ks) {
      int row = (wm << 7) + (mh << 6) + (i << 4) + lr;
      af[i] = *(const bf16x8_t*)(cA + (row << 7) + (((ks << 6) + (g << 4)) ^ ((row & 7) << 4)));
    };
    auto ldB = [&](int j, int ks) {
      int row = (wn << 6) + (j << 4) + lr;
      bfv[j] = *(const bf16x8_t*)(cB + (row << 7) + (((ks << 6) + (g << 4)) ^ ((row & 7) << 4)));
    };

    // ---- phase 0: mh0, ks0 ----
#pragma unroll
    for (int i = 0; i < 4; ++i) ldA(i, 0, 0);
#pragma unroll
    for (int j = 0; j < 4; ++j) ldB(j, 0);
    if (st) { stageA(0, kn, bnx); stageA(2, kn, bnx); }
    GSYNC1;
    __builtin_amdgcn_s_setprio(1);
#pragma unroll
    for (int i = 0; i < 4; ++i)
#pragma unroll
      for (int j = 0; j < 4; ++j)
        acc[i][j] = __builtin_amdgcn_mfma_f32_16x16x32_bf16(af[i], bfv[j], acc[i][j], 0, 0, 0);
    __builtin_amdgcn_s_setprio(0);
    GSYNC2(st);

    // ---- phase 1: mh1, ks0 ----
#pragma unroll
    for (int i = 0; i < 4; ++i) ldA(i, 1, 0);
    if (st) { stageB(0, kn, bnx); stageB(1, kn, bnx); }
    GSYNC1;
    __builtin_amdgcn_s_setprio(1);
#pragma unroll
    for (int i = 0; i < 4; ++i)
#pragma unroll
      for (int j = 0; j < 4; ++j)
        acc[4 + i][j] = __builtin_amdgcn_mfma_f32_16x16x32_bf16(af[i], bfv[j], acc[4 + i][j], 0, 0, 0);
    __builtin_amdgcn_s_setprio(0);
    GSYNC2(st);

    // ---- phase 2: mh0, ks1 ----
#pragma unroll
    for (int i = 0; i < 4; ++i) ldA(i, 0, 1);
#pragma unroll
    for (int j = 0; j < 4; ++j) ldB(j, 1);
    if (st) { stageB(2, kn, bnx); stageB(3, kn, bnx); }
    GSYNC1;
    __builtin_amdgcn_s_setprio(1);
#pragma unroll
    for (int i = 0; i < 4; ++i)
#pragma unroll
      for (int j = 0; j < 4; ++j)
        acc[i][j] = __builtin_amdgcn_mfma_f32_16x16x32_bf16(af[i], bfv[j], acc[i][j], 0, 0, 0);
    __builtin_amdgcn_s_setprio(0);
    GSYNC2(st);

    // ---- phase 3: mh1, ks1 ----
#pragma unroll
    for (int i = 0; i < 4; ++i) ldA(i, 1, 1);
    if (st) { stageA(1, kn, bnx); stageA(3, kn, bnx); }
    GSYNC1;
    __builtin_amdgcn_s_setprio(1);
#pragma unroll
    for (int i = 0; i < 4; ++i)
#pragma unroll
      for (int j = 0; j < 4; ++j)
        acc[4 + i][j] = __builtin_amdgcn_mfma_f32_16x16x32_bf16(af[i], bfv[j], acc[4 + i][j], 0, 0, 0);
    __builtin_amdgcn_s_setprio(0);
    GSYNC2(st);
  }

  // ---- epilogue: stage tile in LDS, then wide (rope-fused) stores ----
  __syncthreads();
  const bool trstage = (EPI == 5) && (n0 >= 2048);
  if (trstage) {
#pragma unroll
    for (int i = 0; i < 8; ++i)
#pragma unroll
      for (int j = 0; j < 4; ++j) {
        int col = (wn << 6) + (j << 4) + lr;
#pragma unroll
        for (int r = 0; r < 4; ++r) {
          int row = (wm << 7) + (i << 4) + (g << 2) + r;
          *(ushort*)(lds + (col << 9) + ((row << 1) ^ ((col & 7) << 4))) = f2bf(acc[i][j][r]);
        }
      }
  } else {
#pragma unroll
    for (int i = 0; i < 8; ++i)
#pragma unroll
      for (int j = 0; j < 4; ++j) {
        int col = (wn << 6) + (j << 4) + lr;
#pragma unroll
        for (int r = 0; r < 4; ++r) {
          int row = (wm << 7) + (i << 4) + (g << 2) + r;
          *(ushort*)(lds + (row << 9) + ((col << 1) ^ ((row & 7) << 4))) = f2bf(acc[i][j][r]);
        }
      }
  }
  __syncthreads();

  // rope-fused store of one [256][256] tile (one head wide): d = ch*8..+7
  auto ropeStore = [&](ushort* C, int ldc) {
#pragma unroll
    for (int it = 0; it < 16; ++it) {
      int idx = it * 512 + t;
      int row = idx >> 5, ch = idx & 31;
      uint4 v = *(const uint4*)(lds + (row << 9) + ((ch << 4) ^ ((row & 7) << 4)));
      uint4 p = *(const uint4*)(lds + (row << 9) + (((ch ^ 16) << 4) ^ ((row & 7) << 4)));
      int pos = (m0 + row) & (NS - 1);
      int d0 = ch << 3;
      float4 c0 = *(const float4*)(cosT + (size_t)pos * 256 + d0);
      float4 c1 = *(const float4*)(cosT + (size_t)pos * 256 + d0 + 4);
      float4 s0 = *(const float4*)(sinT + (size_t)pos * 256 + d0);
      float4 s1 = *(const float4*)(sinT + (size_t)pos * 256 + d0 + 4);
      float cs[8] = {c0.x, c0.y, c0.z, c0.w, c1.x, c1.y, c1.z, c1.w};
      float ss[8] = {s0.x, s0.y, s0.z, s0.w, s1.x, s1.y, s1.z, s1.w};
      const float sgn = (ch < 16) ? -1.f : 1.f;
      const ushort* vv = (const ushort*)&v;
      const ushort* pp = (const ushort*)&p;
      ushort o[8];
#pragma unroll
      for (int e = 0; e < 8; ++e)
        o[e] = f2bf(bf2f(vv[e]) * cs[e] + sgn * bf2f(pp[e]) * ss[e]);
      *(uint4*)(C + (size_t)(m0 + row) * ldc + n0 % ((EPI == 5) ? 2048 : (1 << 30)) + (ch << 3)) = *(const uint4*)o;
    }
  };

  if (EPI == 1) {
    ushort* C = (ushort*)Cout;
#pragma unroll
    for (int it = 0; it < 16; ++it) {
      int idx = it * 512 + t;
      int row = idx >> 5, ch = idx & 31;
      uint4 v = *(const uint4*)(lds + (row << 9) + ((ch << 4) ^ ((row & 7) << 4)));
      uint4 p = *(const uint4*)(lds + (row << 9) + (((ch ^ 16) << 4) ^ ((row & 7) << 4)));
      int pos = (m0 + row) & (NS - 1);
      int d0 = ch << 3;
      float4 c0 = *(const float4*)(cosT + (size_t)pos * 256 + d0);
      float4 c1 = *(const float4*)(cosT + (size_t)pos * 256 + d0 + 4);
      float4 s0 = *(const float4*)(sinT + (size_t)pos * 256 + d0);
      float4 s1 = *(const float4*)(sinT + (size_t)pos * 256 + d0 + 4);
      float cs[8] = {c0.x, c0.y, c0.z, c0.w, c1.x, c1.y, c1.z, c1.w};
      float ss[8] = {s0.x, s0.y, s0.z, s0.w, s1.x, s1.y, s1.z, s1.w};
      const float sgn = (ch < 16) ? -1.f : 1.f;
      const ushort* vv = (const ushort*)&v;
      const ushort* pp = (const ushort*)&p;
      ushort o[8];
#pragma unroll
      for (int e = 0; e < 8; ++e)
        o[e] = f2bf(bf2f(vv[e]) * cs[e] + sgn * bf2f(pp[e]) * ss[e]);
      *(uint4*)(C + (size_t)(m0 + row) * N + n0 + (ch << 3)) = *(const uint4*)o;
    }
  } else if (EPI == 5) {
    ushort* C = (ushort*)Cout;
    if (n0 < 2048) {  // K half -> kbuf, WITH RoPE
#pragma unroll
      for (int it = 0; it < 16; ++it) {
        int idx = it * 512 + t;
        int row = idx >> 5, ch = idx & 31;
        uint4 v = *(const uint4*)(lds + (row << 9) + ((ch << 4) ^ ((row & 7) << 4)));
        uint4 p = *(const uint4*)(lds + (row << 9) + (((ch ^ 16) << 4) ^ ((row & 7) << 4)));
        int pos = (m0 + row) & (NS - 1);
        int d0 = ch << 3;
        float4 c0 = *(const float4*)(cosT + (size_t)pos * 256 + d0);
        float4 c1 = *(const float4*)(cosT + (size_t)pos * 256 + d0 + 4);
        float4 s0 = *(const float4*)(sinT + (size_t)pos * 256 + d0);
        float4 s1 = *(const float4*)(sinT + (size_t)pos * 256 + d0 + 4);
        float cs[8] = {c0.x, c0.y, c0.z, c0.w, c1.x, c1.y, c1.z, c1.w};
        float ss[8] = {s0.x, s0.y, s0.z, s0.w, s1.x, s1.y, s1.z, s1.w};
        const float sgn = (ch < 16) ? -1.f : 1.f;
        const ushort* vv = (const ushort*)&v;
        const ushort* pp = (const ushort*)&p;
        ushort o[8];
#pragma unroll
        for (int e = 0; e < 8; ++e)
          o[e] = f2bf(bf2f(vv[e]) * cs[e] + sgn * bf2f(pp[e]) * ss[e]);
        *(uint4*)(C + (size_t)(m0 + row) * 2048 + n0 + (ch << 3)) = *(const uint4*)o;
      }
    } else {
      // V half -> tiled vtbuf (no rope). Fully linear store: elem = base + s*8.
      ushort* vC = C + (size_t)4096 * 2048;
      const int plane = (m0 >> 11) * NKVH + ((n0 - 2048) >> 8);
      ushort* dst = vC + (size_t)plane * ((size_t)NS * DH) + (size_t)((m0 & (NS - 1)) >> 5) * 8192;
#pragma unroll
      for (int it = 0; it < 16; ++it) {
        int s = it * 512 + t;
        int lr2 = s & 7, kq = (s >> 3) & 7, dt_l = (s >> 6) & 15, sb_l = s >> 10;
        int d0 = (dt_l << 4) + (lr2 << 1);   // lds col
        int r0 = (sb_l << 5) + (kq << 2);    // lds row (token)
        uint2 a = *(const uint2*)(lds + (d0 << 9) + ((r0 << 1) ^ ((d0 & 7) << 4)));
        uint2 b2 = *(const uint2*)(lds + ((d0 + 1) << 9) + ((r0 << 1) ^ (((d0 + 1) & 7) << 4)));
        uint4 v; v.x = a.x; v.y = a.y; v.z = b2.x; v.w = b2.y;
        *(uint4*)(dst + (size_t)s * 8) = v;
      }
    }
  } else {
    float* Cf = (float*)Cout;
#pragma unroll
    for (int it = 0; it < 32; ++it) {
      int idx = it * 512 + t;
      int row = idx >> 6, qd = idx & 63;
      ushort4 hv = *(const ushort4*)(lds + (row << 9) + ((qd << 3) ^ ((row & 7) << 4)));
      float4 fv;
      fv.x = bf2f(hv.x); fv.y = bf2f(hv.y); fv.z = bf2f(hv.z); fv.w = bf2f(hv.w);
      *(float4*)(Cf + (size_t)(m0 + row) * N + n0 + (qd << 2)) = fv;
    }
  }
}

// ---------------- flash attention v4: QBLK=128, 8 waves, dbuf gload16 ------
// (round-12 kernel, measured 190us) grid: B*NH*(S/128) = 512; block 512 = 8
// waves, each wave 16 q-rows. 64KB LDS dbuf -> 2 blocks/CU. V in attn-tiled
// global layout -> fully linear gload16, bank-bijective PV reads. K: chunk XOR
// (row&7). Fixed-max softmax (softcap bounds |logit|<=50).
__global__ __launch_bounds__(512) void attn_kernel(const ushort* __restrict__ q,
                                                   const ushort* __restrict__ k,
                                                   const ushort* __restrict__ vt,
                                                   ushort* __restrict__ ao) {
  __shared__ alignas(16) char lK[2][16384];
  __shared__ alignas(16) char lV[2][16384];
  const int bid = (int)blockIdx.x;
  const int qb = bid & 15;
  const int h = (bid >> 4) & 15;
  const int b = bid >> 8;
  const int kvh = h >> 1;
  const int qb0 = qb << 7;
  const int t = threadIdx.x;
  const int lane = t & 63;
  const int w = t >> 6;
  const int g = lane >> 4;
  const int lr = lane & 15;

  const int qrow = qb0 + (w << 4) + lr;
  bf16x8_t qf[8];
  const ushort* qbase = q + (size_t)(b * NS + qrow) * (NHEADS * DH) + h * DH;
#pragma unroll
  for (int ks = 0; ks < 8; ++ks)
    qf[ks] = *(const bf16x8_t*)(qbase + (ks << 5) + (g << 3));

  float l_r = 0.f;
  f32x4_t oacc[16] = {};

  const int qminw = qb0 + (w << 4);
  const int qmaxw = qminw + 15;
  int t_lo = qb0 - (WIN - 1);
  if (t_lo < 0) t_lo = 0;
  t_lo &= ~31;
  const int t_hi = qb0 + 127;
  const int nt = ((t_hi - t_lo) >> 5) + 1;

  const ushort* kgb = k + (size_t)(b * NS) * (NKVH * DH) + kvh * DH;
  const ushort* vgb = vt + (size_t)(b * NKVH + kvh) * ((size_t)NS * DH);

  auto stage = [&](int kt, int bi) {
    char* dk = lK[bi];
    char* dv = lV[bi];
    const int sb = kt >> 5;
#pragma unroll
    for (int j = 0; j < 2; ++j) {
      int i = (w << 1) + j;
      // K: issue i stages rows 2i, 2i+1 (1KB); source chunk pre-swizzled.
      int row = (i << 1) + (lane >> 5);
      int ck = (lane & 31) ^ (row & 7);
      gload16(kgb + (size_t)(kt + row) * (NKVH * DH) + (ck << 3), dk + (i << 10));
      // V: tiled layout, fully linear (16KB contiguous per 32-key tile).
      gload16(vgb + (size_t)sb * 8192 + (((i << 6) + lane) << 3), dv + (i << 10));
    }
  };

  int cur = 0;
  stage(t_lo, 0);
  __syncthreads();

  for (int i = 0; i < nt; ++i) {
    const int kt = t_lo + (i << 5);
    if (i + 1 < nt) stage(kt + 32, cur ^ 1);  // async prefetch into other buf
    const char* lk = lK[cur];
    const char* lv = lV[cur];
#pragma unroll
    for (int sub = 0; sub < 2; ++sub) {
      const int key0 = kt + (sub << 4);
      if (key0 > qmaxw) continue;
      if (key0 + 15 < qminw - (WIN - 1)) continue;

      f32x4_t sacc = {};
      __builtin_amdgcn_s_setprio(1);
#pragma unroll
      for (int ks = 0; ks < 8; ++ks) {
        int row = (sub << 4) + lr;
        bf16x8_t kf = *(const bf16x8_t*)(lk + (((row << 9) + (ks << 6) + (g << 4)) ^ ((row & 7) << 4)));
        sacc = __builtin_amdgcn_mfma_f32_16x16x32_bf16(kf, qf[ks], sacc, 0, 0, 0);
      }
      __builtin_amdgcn_s_setprio(0);

      float pvv[4];
      const bool full = (key0 + 15 <= qminw) && (key0 >= qmaxw - (WIN - 1));
      if (full) {
#pragma unroll
        for (int r = 0; r < 4; ++r) { pvv[r] = pexp(sacc[r]); l_r += pvv[r]; }
      } else {
#pragma unroll
        for (int r = 0; r < 4; ++r) {
          int key = key0 + (g << 2) + r;
          bool ok = (key <= qrow) && (qrow - key < WIN);
          pvv[r] = ok ? pexp(sacc[r]) : 0.f;
          l_r += pvv[r];
        }
      }

      s16x4_t pa;
      pa[0] = (short)f2bf(pvv[0]);
      pa[1] = (short)f2bf(pvv[1]);
      pa[2] = (short)f2bf(pvv[2]);
      pa[3] = (short)f2bf(pvv[3]);

      const int kqoff = ((sub << 2) + g) << 7;  // kq*128 bytes
      __builtin_amdgcn_s_setprio(1);
#pragma unroll
      for (int dt = 0; dt < 16; ++dt) {
        s16x4_t vf = *(const s16x4_t*)(lv + (dt << 10) + kqoff + (lr << 3));
        oacc[dt] = mfma_pv(pa, vf, oacc[dt]);
      }
      __builtin_amdgcn_s_setprio(0);
    }
    __syncthreads();  // drains gloads (next tile ready) + all waves done with cur
    cur ^= 1;
  }

  l_r += __shfl_xor(l_r, 16);
  l_r += __shfl_xor(l_r, 32);
  float dn[4];
#pragma unroll
  for (int r = 0; r < 4; ++r)
    dn[r] = 1.0f / __shfl(l_r, (g << 2) + r);

  const int orow0 = b * NS + qb0 + (w << 4) + (g << 2);
#pragma unroll
  for (int dt = 0; dt < 16; ++dt) {
    int col = h * DH + (dt << 4) + lr;
#pragma unroll
    for (int r = 0; r < 4; ++r) {
      ao[(size_t)(orow0 + r) * (NHEADS * DH) + col] = f2bf(oacc[dt][r] * dn[r]);
    }
  }
}

extern "C" void kernel_launch(void* const* d_in, const int* in_sizes, int n_in,
                              void* d_out, int out_size, void* d_ws, size_t ws_size,
                              hipStream_t stream) {
  const float* hs   = (const float*)d_in[0];
  const float* sint = (const float*)d_in[3];
  const float* cost = (const float*)d_in[4];
  const float* Wq = (const float*)d_in[6];
  const float* Wk = (const float*)d_in[7];
  const float* Wv = (const float*)d_in[8];
  const float* Wo = (const float*)d_in[9];

  char* ws = (char*)d_ws;
  size_t off = 0;
  auto alloc = [&](size_t bytes) {
    char* p = ws + off;
    off += (bytes + 255) & ~(size_t)255;
    return p;
  };
  ushort* hsb   = (ushort*)alloc((size_t)4096 * 3584 * 2);  // hs in bf16
  ushort* wT    = (ushort*)alloc((size_t)4096 * 3584 * 2);  // reused weight^T buffer
  ushort* qbuf  = (ushort*)alloc((size_t)4096 * 4096 * 2);
  ushort* kbuf  = (ushort*)alloc((size_t)4096 * 2048 * 2);  // MUST precede vtbuf
  ushort* vtbuf = (ushort*)alloc((size_t)4096 * 2048 * 2);  // = kbuf + 4096*2048 (tiled)
  ushort* aobuf = qbuf;  // alias: attn writes exactly the region only it reads
  if (off > ws_size) return;

  // hs f32 -> bf16
  f32_to_bf16_kernel<<<(4096 * 3584 / 4) / 256, 256, 0, stream>>>(hs, hsb, 4096 * 3584 / 4);

  // fused K+V projection (RoPE fused on K half): Bt = [WkT; WvT] stacked in wT
  transpose_f32_bf16<<<(3584 / 64) * (2048 / 64), 256, 0, stream>>>(Wk, wT, 3584, 2048);
  transpose_f32_bf16<<<(3584 / 64) * (2048 / 64), 256, 0, stream>>>(Wv, wT + (size_t)2048 * 3584, 3584, 2048);
  gemm256<5><<<16 * 16, 512, 0, stream>>>(hsb, wT, kbuf, sint, cost, 4096, 4096, 3584);

  // Q projection (RoPE fused)
  transpose_f32_bf16<<<(3584 / 64) * (4096 / 64), 256, 0, stream>>>(Wq, wT, 3584, 4096);
  gemm256<1><<<16 * 16, 512, 0, stream>>>(hsb, wT, qbuf, sint, cost, 4096, 4096, 3584);

  // attention: QBLK=128, 8 waves (ao aliases qbuf)
  attn_kernel<<<NB * NHEADS * (NS / 128), 512, 0, stream>>>(qbuf, kbuf, vtbuf, aobuf);

  // output projection, f32 out
  transpose_f32_bf16<<<(4096 / 64) * (3584 / 64), 256, 0, stream>>>(Wo, wT, 4096, 3584);
  gemm256<2><<<16 * 14, 512, 0, stream>>>(aobuf, wT, d_out, nullptr, nullptr, 4096, 3584, 4096);
}

// Round 15
// 564.262 us; speedup vs baseline: 1.4451x; 1.0408x over previous
//
#include <hip/hip_runtime.h>
#include <hip/hip_bf16.h>

typedef __bf16 bf16x8_t __attribute__((ext_vector_type(8)));
typedef __bf16 bf16x4_t __attribute__((ext_vector_type(4)));
typedef short s16x4_t  __attribute__((ext_vector_type(4)));
typedef float f32x4_t  __attribute__((ext_vector_type(4)));

#define NB 2
#define NS 2048
#define NHID 3584
#define NHEADS 16
#define NKVH 8
#define DH 256
#define WIN 1024

__device__ __forceinline__ float bf2f(ushort u) {
  union { unsigned v; float f; } x; x.v = ((unsigned)u) << 16; return x.f;
}
__device__ __forceinline__ ushort f2bf(float f) {
  unsigned x = __builtin_bit_cast(unsigned, f);
  unsigned r = (x + 0x7fffu + ((x >> 16) & 1u)) >> 16;
  return (ushort)r;
}

__device__ __forceinline__ void gload16(const void* g, void* l) {
  __builtin_amdgcn_global_load_lds((const __attribute__((address_space(1))) void*)g,
                                   (__attribute__((address_space(3))) void*)l, 16, 0, 0);
}

__device__ __forceinline__ f32x4_t mfma_pv(s16x4_t a, s16x4_t b, f32x4_t c) {
#if __has_builtin(__builtin_amdgcn_mfma_f32_16x16x16_bf16)
  return __builtin_amdgcn_mfma_f32_16x16x16_bf16(
      __builtin_bit_cast(bf16x4_t, a), __builtin_bit_cast(bf16x4_t, b), c, 0, 0, 0);
#else
  return __builtin_amdgcn_mfma_f32_16x16x16bf16_1k(a, b, c, 0, 0, 0);
#endif
}

// p = exp(50*tanh((s/16)/50)); x = s/800; bounded by e^50 (fixed-max softmax safe)
__device__ __forceinline__ float pexp(float s) {
  float e = __expf(fminf(s * 0.0025f, 80.f));
  float th = __fdividef(e - 1.f, e + 1.f);
  return __expf(50.f * th);
}

// ---------------- f32 -> bf16 elementwise convert (x4 vectorized) ---------
__global__ __launch_bounds__(256) void f32_to_bf16_kernel(const float* __restrict__ in,
                                                          ushort* __restrict__ out, int n4) {
  int i = (int)blockIdx.x * 256 + (int)threadIdx.x;
  if (i < n4) {
    float4 v = ((const float4*)in)[i];
    ushort4 o;
    o.x = f2bf(v.x); o.y = f2bf(v.y); o.z = f2bf(v.z); o.w = f2bf(v.w);
    ((ushort4*)out)[i] = o;
  }
}

// ------------- transpose+convert: f32 in[R][C] -> bf16 out[C][R] ----------
__global__ __launch_bounds__(256) void transpose_f32_bf16(const float* __restrict__ in,
                                                          ushort* __restrict__ out,
                                                          int R, int Cc) {
  __shared__ ushort tile[64][72];
  const int t = threadIdx.x;
  const int ct = Cc >> 6;
  const int by = blockIdx.x / ct;
  const int bx = blockIdx.x % ct;
  const int r0 = by << 6, c0 = bx << 6;
#pragma unroll
  for (int i = 0; i < 16; ++i) {
    int idx = i * 256 + t;
    int r = idx >> 6, c = idx & 63;
    tile[r][c] = f2bf(in[(size_t)(r0 + r) * Cc + c0 + c]);
  }
  __syncthreads();
#pragma unroll
  for (int i = 0; i < 16; ++i) {
    int idx = i * 256 + t;
    int rr = idx >> 6, cc = idx & 63;
    out[(size_t)(c0 + rr) * R + r0 + cc] = tile[cc][rr];
  }
}

// ============ 8-phase 256x256 GEMM: C = A[M][K] * Bt[N][K]^T ==============
#define GSYNC1 do { __builtin_amdgcn_s_barrier(); \
    asm volatile("s_waitcnt lgkmcnt(0)" ::: "memory"); \
    __builtin_amdgcn_sched_barrier(0); } while (0)
#define GSYNC2(st) do { \
    if (st) asm volatile("s_waitcnt vmcnt(2)" ::: "memory"); \
    else    asm volatile("s_waitcnt vmcnt(0)" ::: "memory"); \
    __builtin_amdgcn_sched_barrier(0); \
    __builtin_amdgcn_s_barrier(); } while (0)

// EPI=1: bf16 C[M][N] + fused RoPE (tile N=256 = one head; pairs (d,d+128)
//        in-tile; sin/cos tables have duplicated halves so index [pos*256+d]).
// EPI=2: f32 C (no rope). EPI=5: fused KV — K half -> kbuf rows WITH RoPE;
// V half -> vtbuf ATTN-TILED (no rope): elem(b,kvh,s,d) =
//   plane*524288 + (s>>5)*8192 + (d>>4)*512 + ((s&31)>>2)*64 + (d&15)*4 + (s&3)
template <int EPI>
__global__ __launch_bounds__(512, 2) void gemm256(const ushort* __restrict__ A,
                                                  const ushort* __restrict__ Bt,
                                                  void* __restrict__ Cout,
                                                  const float* __restrict__ sinT,
                                                  const float* __restrict__ cosT,
                                                  int M, int N, int K) {
  __shared__ alignas(16) char lds[131072];
  const int t = threadIdx.x;
  const int lane = t & 63;
  const int wid = t >> 6;
  const int wm = wid >> 2;   // 0..1
  const int wn = wid & 3;    // 0..3
  const int g = lane >> 4;
  const int lr = lane & 15;
  const int lrow8 = lane >> 3;
  const int lp = (lane & 7) ^ lrow8;  // pre-swizzled staging chunk

  const int nbn = N >> 8;
  const int nwg = (int)gridDim.x;
  const int bid = (int)blockIdx.x;
  const int swz = (bid & 7) * (nwg >> 3) + (bid >> 3);
  const int bm = swz / nbn, bn = swz % nbn;
  const int m0 = bm << 8, n0 = bn << 8;

  f32x4_t acc[8][4] = {};
  const int T = K >> 6;

  auto stageA = [&](int q, int koff, int bufn) {
    int row = (q << 6) + (wid << 3) + lrow8;
    gload16(A + (size_t)(m0 + row) * K + koff + (lp << 3),
            lds + bufn * 32768 + (q << 13) + (wid << 10));
  };
  auto stageB = [&](int q, int koff, int bufn) {
    int row = (q << 6) + (wid << 3) + lrow8;
    gload16(Bt + (size_t)(n0 + row) * K + koff + (lp << 3),
            lds + 65536 + bufn * 32768 + (q << 13) + (wid << 10));
  };

  // prologue: tile 0 -> buf 0
#pragma unroll
  for (int q = 0; q < 4; ++q) { stageA(q, 0, 0); stageB(q, 0, 0); }
  asm volatile("s_waitcnt vmcnt(0)" ::: "memory");
  __builtin_amdgcn_s_barrier();

  for (int tt = 0; tt < T; ++tt) {
    const int bc = tt & 1;
    const int bnx = bc ^ 1;
    const bool st = (tt + 1 < T);
    const int kn = (tt + 1) << 6;
    const char* cA = lds + bc * 32768;
    const char* cB = lds + 65536 + bc * 32768;
    bf16x8_t af[4], bfv[4];

    auto ldA = [&](int i, int mh, int ks) {
      int row = (wm << 7) + (mh << 6) + (i << 4) + lr;
      af[i] = *(const bf16x8_t*)(cA + (row << 7) + (((ks << 6) + (g << 4)) ^ ((row & 7) << 4)));
    };
    auto ldB = [&](int j, int ks) {
      int row = (wn << 6) + (j << 4) + lr;
      bfv[j] = *(const bf16x8_t*)(cB + (row << 7) + (((ks << 6) + (g << 4)) ^ ((row & 7) << 4)));
    };

    // ---- phase 0: mh0, ks0 ----
#pragma unroll
    for (int i = 0; i < 4; ++i) ldA(i, 0, 0);
#pragma unroll
    for (int j = 0; j < 4; ++j) ldB(j, 0);
    if (st) { stageA(0, kn, bnx); stageA(2, kn, bnx); }
    GSYNC1;
    __builtin_amdgcn_s_setprio(1);
#pragma unroll
    for (int i = 0; i < 4; ++i)
#pragma unroll
      for (int j = 0; j < 4; ++j)
        acc[i][j] = __builtin_amdgcn_mfma_f32_16x16x32_bf16(af[i], bfv[j], acc[i][j], 0, 0, 0);
    __builtin_amdgcn_s_setprio(0);
    GSYNC2(st);

    // ---- phase 1: mh1, ks0 ----
#pragma unroll
    for (int i = 0; i < 4; ++i) ldA(i, 1, 0);
    if (st) { stageB(0, kn, bnx); stageB(1, kn, bnx); }
    GSYNC1;
    __builtin_amdgcn_s_setprio(1);
#pragma unroll
    for (int i = 0; i < 4; ++i)
#pragma unroll
      for (int j = 0; j < 4; ++j)
        acc[4 + i][j] = __builtin_amdgcn_mfma_f32_16x16x32_bf16(af[i], bfv[j], acc[4 + i][j], 0, 0, 0);
    __builtin_amdgcn_s_setprio(0);
    GSYNC2(st);

    // ---- phase 2: mh0, ks1 ----
#pragma unroll
    for (int i = 0; i < 4; ++i) ldA(i, 0, 1);
#pragma unroll
    for (int j = 0; j < 4; ++j) ldB(j, 1);
    if (st) { stageB(2, kn, bnx); stageB(3, kn, bnx); }
    GSYNC1;
    __builtin_amdgcn_s_setprio(1);
#pragma unroll
    for (int i = 0; i < 4; ++i)
#pragma unroll
      for (int j = 0; j < 4; ++j)
        acc[i][j] = __builtin_amdgcn_mfma_f32_16x16x32_bf16(af[i], bfv[j], acc[i][j], 0, 0, 0);
    __builtin_amdgcn_s_setprio(0);
    GSYNC2(st);

    // ---- phase 3: mh1, ks1 ----
#pragma unroll
    for (int i = 0; i < 4; ++i) ldA(i, 1, 1);
    if (st) { stageA(1, kn, bnx); stageA(3, kn, bnx); }
    GSYNC1;
    __builtin_amdgcn_s_setprio(1);
#pragma unroll
    for (int i = 0; i < 4; ++i)
#pragma unroll
      for (int j = 0; j < 4; ++j)
        acc[4 + i][j] = __builtin_amdgcn_mfma_f32_16x16x32_bf16(af[i], bfv[j], acc[4 + i][j], 0, 0, 0);
    __builtin_amdgcn_s_setprio(0);
    GSYNC2(st);
  }

  // ---- epilogue: stage tile in LDS, then wide (rope-fused) stores ----
  __syncthreads();
  const bool trstage = (EPI == 5) && (n0 >= 2048);
  if (trstage) {
#pragma unroll
    for (int i = 0; i < 8; ++i)
#pragma unroll
      for (int j = 0; j < 4; ++j) {
        int col = (wn << 6) + (j << 4) + lr;
#pragma unroll
        for (int r = 0; r < 4; ++r) {
          int row = (wm << 7) + (i << 4) + (g << 2) + r;
          *(ushort*)(lds + (col << 9) + ((row << 1) ^ ((col & 7) << 4))) = f2bf(acc[i][j][r]);
        }
      }
  } else {
#pragma unroll
    for (int i = 0; i < 8; ++i)
#pragma unroll
      for (int j = 0; j < 4; ++j) {
        int col = (wn << 6) + (j << 4) + lr;
#pragma unroll
        for (int r = 0; r < 4; ++r) {
          int row = (wm << 7) + (i << 4) + (g << 2) + r;
          *(ushort*)(lds + (row << 9) + ((col << 1) ^ ((row & 7) << 4))) = f2bf(acc[i][j][r]);
        }
      }
  }
  __syncthreads();

  if (EPI == 1) {
    ushort* C = (ushort*)Cout;
#pragma unroll
    for (int it = 0; it < 16; ++it) {
      int idx = it * 512 + t;
      int row = idx >> 5, ch = idx & 31;
      uint4 v = *(const uint4*)(lds + (row << 9) + ((ch << 4) ^ ((row & 7) << 4)));
      uint4 p = *(const uint4*)(lds + (row << 9) + (((ch ^ 16) << 4) ^ ((row & 7) << 4)));
      int pos = (m0 + row) & (NS - 1);
      int d0 = ch << 3;
      float4 c0 = *(const float4*)(cosT + (size_t)pos * 256 + d0);
      float4 c1 = *(const float4*)(cosT + (size_t)pos * 256 + d0 + 4);
      float4 s0 = *(const float4*)(sinT + (size_t)pos * 256 + d0);
      float4 s1 = *(const float4*)(sinT + (size_t)pos * 256 + d0 + 4);
      float cs[8] = {c0.x, c0.y, c0.z, c0.w, c1.x, c1.y, c1.z, c1.w};
      float ss[8] = {s0.x, s0.y, s0.z, s0.w, s1.x, s1.y, s1.z, s1.w};
      const float sgn = (ch < 16) ? -1.f : 1.f;
      const ushort* vv = (const ushort*)&v;
      const ushort* pp = (const ushort*)&p;
      ushort o[8];
#pragma unroll
      for (int e = 0; e < 8; ++e)
        o[e] = f2bf(bf2f(vv[e]) * cs[e] + sgn * bf2f(pp[e]) * ss[e]);
      *(uint4*)(C + (size_t)(m0 + row) * N + n0 + (ch << 3)) = *(const uint4*)o;
    }
  } else if (EPI == 5) {
    ushort* C = (ushort*)Cout;
    if (n0 < 2048) {  // K half -> kbuf, WITH RoPE
#pragma unroll
      for (int it = 0; it < 16; ++it) {
        int idx = it * 512 + t;
        int row = idx >> 5, ch = idx & 31;
        uint4 v = *(const uint4*)(lds + (row << 9) + ((ch << 4) ^ ((row & 7) << 4)));
        uint4 p = *(const uint4*)(lds + (row << 9) + (((ch ^ 16) << 4) ^ ((row & 7) << 4)));
        int pos = (m0 + row) & (NS - 1);
        int d0 = ch << 3;
        float4 c0 = *(const float4*)(cosT + (size_t)pos * 256 + d0);
        float4 c1 = *(const float4*)(cosT + (size_t)pos * 256 + d0 + 4);
        float4 s0 = *(const float4*)(sinT + (size_t)pos * 256 + d0);
        float4 s1 = *(const float4*)(sinT + (size_t)pos * 256 + d0 + 4);
        float cs[8] = {c0.x, c0.y, c0.z, c0.w, c1.x, c1.y, c1.z, c1.w};
        float ss[8] = {s0.x, s0.y, s0.z, s0.w, s1.x, s1.y, s1.z, s1.w};
        const float sgn = (ch < 16) ? -1.f : 1.f;
        const ushort* vv = (const ushort*)&v;
        const ushort* pp = (const ushort*)&p;
        ushort o[8];
#pragma unroll
        for (int e = 0; e < 8; ++e)
          o[e] = f2bf(bf2f(vv[e]) * cs[e] + sgn * bf2f(pp[e]) * ss[e]);
        *(uint4*)(C + (size_t)(m0 + row) * 2048 + n0 + (ch << 3)) = *(const uint4*)o;
      }
    } else {
      // V half -> tiled vtbuf (no rope). Fully linear store: elem = base + s*8.
      ushort* vC = C + (size_t)4096 * 2048;
      const int plane = (m0 >> 11) * NKVH + ((n0 - 2048) >> 8);
      ushort* dst = vC + (size_t)plane * ((size_t)NS * DH) + (size_t)((m0 & (NS - 1)) >> 5) * 8192;
#pragma unroll
      for (int it = 0; it < 16; ++it) {
        int s = it * 512 + t;
        int lr2 = s & 7, kq = (s >> 3) & 7, dt_l = (s >> 6) & 15, sb_l = s >> 10;
        int d0 = (dt_l << 4) + (lr2 << 1);   // lds col
        int r0 = (sb_l << 5) + (kq << 2);    // lds row (token)
        uint2 a = *(const uint2*)(lds + (d0 << 9) + ((r0 << 1) ^ ((d0 & 7) << 4)));
        uint2 b2 = *(const uint2*)(lds + ((d0 + 1) << 9) + ((r0 << 1) ^ (((d0 + 1) & 7) << 4)));
        uint4 v; v.x = a.x; v.y = a.y; v.z = b2.x; v.w = b2.y;
        *(uint4*)(dst + (size_t)s * 8) = v;
      }
    }
  } else {
    float* Cf = (float*)Cout;
#pragma unroll
    for (int it = 0; it < 32; ++it) {
      int idx = it * 512 + t;
      int row = idx >> 6, qd = idx & 63;
      ushort4 hv = *(const ushort4*)(lds + (row << 9) + ((qd << 3) ^ ((row & 7) << 4)));
      float4 fv;
      fv.x = bf2f(hv.x); fv.y = bf2f(hv.y); fv.z = bf2f(hv.z); fv.w = bf2f(hv.w);
      *(float4*)(Cf + (size_t)(m0 + row) * N + n0 + (qd << 2)) = fv;
    }
  }
}

// ---------------- flash attention v6: QBLK=64 dbuf + tiled-V + LPT decode --
// grid 1024. Decode: xcd=bid&7 -> planes {2x,2x+1} only (KV 4MB/plane = one
// XCD L2, one plane hot per round); rounds dispatch HEAVY q-blocks first
// (dynamic pickup ~ LPT scheduling -> near-constant CU load; light rounds
// paired ascending/descending). Body = round-8 structure (proven 190us) with
// round-12's tiled-V (fully linear gload16, bank-bijective PV reads).
__global__ __launch_bounds__(256) void attn_kernel(const ushort* __restrict__ q,
                                                   const ushort* __restrict__ k,
                                                   const ushort* __restrict__ vt,
                                                   ushort* __restrict__ ao) {
  __shared__ alignas(16) char lK[2][16384];
  __shared__ alignas(16) char lV[2][16384];
  const int bid = (int)blockIdx.x;
  const int x = bid & 7;
  const int s_ = bid >> 3;       // 0..127
  const int rnd = s_ >> 5;       // 0..3
  const int c = s_ & 31;
  const int a = c >> 1;
  const int hl = c & 1;
  const int plane = (x << 1) | (rnd & 1);
  int qb;
  if (rnd < 2) qb = 16 + a;          // heavy first (LPT)
  else if (rnd == 2) qb = a;         // light ascending
  else qb = 15 - a;                  // light descending
  const int b = plane >> 3;
  const int kvh = plane & 7;
  const int h = (kvh << 1) | hl;
  const int qb0 = qb << 6;
  const int t = threadIdx.x;
  const int lane = t & 63;
  const int w = t >> 6;
  const int g = lane >> 4;
  const int lr = lane & 15;

  const int qrow = qb0 + (w << 4) + lr;
  bf16x8_t qf[8];
  const ushort* qbase = q + (size_t)(b * NS + qrow) * (NHEADS * DH) + h * DH;
#pragma unroll
  for (int ks = 0; ks < 8; ++ks)
    qf[ks] = *(const bf16x8_t*)(qbase + (ks << 5) + (g << 3));

  float l_r = 0.f;
  f32x4_t oacc[16] = {};

  const int qminw = qb0 + (w << 4);
  const int qmaxw = qminw + 15;
  int t_lo = qb0 - (WIN - 1);
  if (t_lo < 0) t_lo = 0;
  t_lo &= ~31;
  const int t_hi = qb0 + 63;
  const int nt = ((t_hi - t_lo) >> 5) + 1;

  const ushort* kgb = k + (size_t)(b * NS) * (NKVH * DH) + kvh * DH;
  const ushort* vgb = vt + (size_t)(b * NKVH + kvh) * ((size_t)NS * DH);  // tiled plane

  auto stage = [&](int kt, int bi) {
    char* dk = lK[bi];
    char* dv = lV[bi];
    const int sb = kt >> 5;
#pragma unroll
    for (int j = 0; j < 4; ++j) {
      int i = (w << 2) + j;  // 0..15
      // K: issue i stages rows 2i, 2i+1 (1KB); source chunk pre-swizzled.
      int row = (i << 1) + (lane >> 5);
      int ck = (lane & 31) ^ (row & 7);
      gload16(kgb + (size_t)(kt + row) * (NKVH * DH) + (ck << 3), dk + (i << 10));
      // V: tiled layout, fully linear (16KB contiguous per 32-key tile).
      gload16(vgb + (size_t)sb * 8192 + (((i << 6) + lane) << 3), dv + (i << 10));
    }
  };

  int cur = 0;
  stage(t_lo, 0);
  __syncthreads();

  for (int i = 0; i < nt; ++i) {
    const int kt = t_lo + (i << 5);
    if (i + 1 < nt) stage(kt + 32, cur ^ 1);  // async prefetch into other buf
    const char* lk = lK[cur];
    const char* lv = lV[cur];
#pragma unroll
    for (int sub = 0; sub < 2; ++sub) {
      const int key0 = kt + (sub << 4);
      if (key0 > qmaxw) continue;
      if (key0 + 15 < qminw - (WIN - 1)) continue;

      f32x4_t sacc = {};
      __builtin_amdgcn_s_setprio(1);
#pragma unroll
      for (int ks = 0; ks < 8; ++ks) {
        int row = (sub << 4) + lr;
        bf16x8_t kf = *(const bf16x8_t*)(lk + (((row << 9) + (ks << 6) + (g << 4)) ^ ((row & 7) << 4)));
        sacc = __builtin_amdgcn_mfma_f32_16x16x32_bf16(kf, qf[ks], sacc, 0, 0, 0);
      }
      __builtin_amdgcn_s_setprio(0);

      float pvv[4];
      const bool full = (key0 + 15 <= qminw) && (key0 >= qmaxw - (WIN - 1));
      if (full) {
#pragma unroll
        for (int r = 0; r < 4; ++r) { pvv[r] = pexp(sacc[r]); l_r += pvv[r]; }
      } else {
#pragma unroll
        for (int r = 0; r < 4; ++r) {
          int key = key0 + (g << 2) + r;
          bool ok = (key <= qrow) && (qrow - key < WIN);
          pvv[r] = ok ? pexp(sacc[r]) : 0.f;
          l_r += pvv[r];
        }
      }

      s16x4_t pa;
      pa[0] = (short)f2bf(pvv[0]);
      pa[1] = (short)f2bf(pvv[1]);
      pa[2] = (short)f2bf(pvv[2]);
      pa[3] = (short)f2bf(pvv[3]);

      const int kqoff = ((sub << 2) + g) << 7;  // kq*128 bytes
      __builtin_amdgcn_s_setprio(1);
#pragma unroll
      for (int dt = 0; dt < 16; ++dt) {
        s16x4_t vf = *(const s16x4_t*)(lv + (dt << 10) + kqoff + (lr << 3));
        oacc[dt] = mfma_pv(pa, vf, oacc[dt]);
      }
      __builtin_amdgcn_s_setprio(0);
    }
    __syncthreads();  // drains gloads (next tile ready) + all waves done with cur
    cur ^= 1;
  }

  l_r += __shfl_xor(l_r, 16);
  l_r += __shfl_xor(l_r, 32);
  float dn[4];
#pragma unroll
  for (int r = 0; r < 4; ++r)
    dn[r] = 1.0f / __shfl(l_r, (g << 2) + r);

  const int orow0 = b * NS + qb0 + (w << 4) + (g << 2);
#pragma unroll
  for (int dt = 0; dt < 16; ++dt) {
    int col = h * DH + (dt << 4) + lr;
#pragma unroll
    for (int r = 0; r < 4; ++r) {
      ao[(size_t)(orow0 + r) * (NHEADS * DH) + col] = f2bf(oacc[dt][r] * dn[r]);
    }
  }
}

extern "C" void kernel_launch(void* const* d_in, const int* in_sizes, int n_in,
                              void* d_out, int out_size, void* d_ws, size_t ws_size,
                              hipStream_t stream) {
  const float* hs   = (const float*)d_in[0];
  const float* sint = (const float*)d_in[3];
  const float* cost = (const float*)d_in[4];
  const float* Wq = (const float*)d_in[6];
  const float* Wk = (const float*)d_in[7];
  const float* Wv = (const float*)d_in[8];
  const float* Wo = (const float*)d_in[9];

  char* ws = (char*)d_ws;
  size_t off = 0;
  auto alloc = [&](size_t bytes) {
    char* p = ws + off;
    off += (bytes + 255) & ~(size_t)255;
    return p;
  };
  ushort* hsb   = (ushort*)alloc((size_t)4096 * 3584 * 2);  // hs in bf16
  ushort* wT    = (ushort*)alloc((size_t)4096 * 3584 * 2);  // reused weight^T buffer
  ushort* qbuf  = (ushort*)alloc((size_t)4096 * 4096 * 2);
  ushort* kbuf  = (ushort*)alloc((size_t)4096 * 2048 * 2);  // MUST precede vtbuf
  ushort* vtbuf = (ushort*)alloc((size_t)4096 * 2048 * 2);  // = kbuf + 4096*2048 (tiled)
  ushort* aobuf = qbuf;  // alias: attn writes exactly the region only it reads
  if (off > ws_size) return;

  // hs f32 -> bf16
  f32_to_bf16_kernel<<<(4096 * 3584 / 4) / 256, 256, 0, stream>>>(hs, hsb, 4096 * 3584 / 4);

  // fused K+V projection (RoPE fused on K half): Bt = [WkT; WvT] stacked in wT
  transpose_f32_bf16<<<(3584 / 64) * (2048 / 64), 256, 0, stream>>>(Wk, wT, 3584, 2048);
  transpose_f32_bf16<<<(3584 / 64) * (2048 / 64), 256, 0, stream>>>(Wv, wT + (size_t)2048 * 3584, 3584, 2048);
  gemm256<5><<<16 * 16, 512, 0, stream>>>(hsb, wT, kbuf, sint, cost, 4096, 4096, 3584);

  // Q projection (RoPE fused)
  transpose_f32_bf16<<<(3584 / 64) * (4096 / 64), 256, 0, stream>>>(Wq, wT, 3584, 4096);
  gemm256<1><<<16 * 16, 512, 0, stream>>>(hsb, wT, qbuf, sint, cost, 4096, 4096, 3584);

  // attention: QBLK=64, LPT/XCD decode (ao aliases qbuf)
  attn_kernel<<<NB * NHEADS * (NS / 64), 256, 0, stream>>>(qbuf, kbuf, vtbuf, aobuf);

  // output projection, f32 out
  transpose_f32_bf16<<<(4096 / 64) * (3584 / 64), 256, 0, stream>>>(Wo, wT, 4096, 3584);
  gemm256<2><<<16 * 14, 512, 0, stream>>>(aobuf, wT, d_out, nullptr, nullptr, 4096, 3584, 4096);
}

// Round 16
// 559.739 us; speedup vs baseline: 1.4567x; 1.0081x over previous
//
#include <hip/hip_runtime.h>
#include <hip/hip_bf16.h>

typedef __bf16 bf16x8_t __attribute__((ext_vector_type(8)));
typedef __bf16 bf16x4_t __attribute__((ext_vector_type(4)));
typedef short s16x4_t  __attribute__((ext_vector_type(4)));
typedef float f32x4_t  __attribute__((ext_vector_type(4)));

#define NB 2
#define NS 2048
#define NHID 3584
#define NHEADS 16
#define NKVH 8
#define DH 256
#define WIN 1024

__device__ __forceinline__ float bf2f(ushort u) {
  union { unsigned v; float f; } x; x.v = ((unsigned)u) << 16; return x.f;
}
__device__ __forceinline__ ushort f2bf(float f) {
  unsigned x = __builtin_bit_cast(unsigned, f);
  unsigned r = (x + 0x7fffu + ((x >> 16) & 1u)) >> 16;
  return (ushort)r;
}

__device__ __forceinline__ void gload16(const void* g, void* l) {
  __builtin_amdgcn_global_load_lds((const __attribute__((address_space(1))) void*)g,
                                   (__attribute__((address_space(3))) void*)l, 16, 0, 0);
}

__device__ __forceinline__ f32x4_t mfma_pv(s16x4_t a, s16x4_t b, f32x4_t c) {
#if __has_builtin(__builtin_amdgcn_mfma_f32_16x16x16_bf16)
  return __builtin_amdgcn_mfma_f32_16x16x16_bf16(
      __builtin_bit_cast(bf16x4_t, a), __builtin_bit_cast(bf16x4_t, b), c, 0, 0, 0);
#else
  return __builtin_amdgcn_mfma_f32_16x16x16bf16_1k(a, b, c, 0, 0, 0);
#endif
}

// p = exp(50*tanh((s/16)/50)); x = s/800; bounded by e^50 (fixed-max softmax safe)
__device__ __forceinline__ float pexp(float s) {
  float e = __expf(fminf(s * 0.0025f, 80.f));
  float th = __fdividef(e - 1.f, e + 1.f);
  return __expf(50.f * th);
}

// ---------------- f32 -> bf16 elementwise convert (x4 vectorized) ---------
__global__ __launch_bounds__(256) void f32_to_bf16_kernel(const float* __restrict__ in,
                                                          ushort* __restrict__ out, int n4) {
  int i = (int)blockIdx.x * 256 + (int)threadIdx.x;
  if (i < n4) {
    float4 v = ((const float4*)in)[i];
    ushort4 o;
    o.x = f2bf(v.x); o.y = f2bf(v.y); o.z = f2bf(v.z); o.w = f2bf(v.w);
    ((ushort4*)out)[i] = o;
  }
}

// ------------- transpose+convert: f32 in[R][C] -> bf16 out[C][R] ----------
__global__ __launch_bounds__(256) void transpose_f32_bf16(const float* __restrict__ in,
                                                          ushort* __restrict__ out,
                                                          int R, int Cc) {
  __shared__ ushort tile[64][72];
  const int t = threadIdx.x;
  const int ct = Cc >> 6;
  const int by = blockIdx.x / ct;
  const int bx = blockIdx.x % ct;
  const int r0 = by << 6, c0 = bx << 6;
#pragma unroll
  for (int i = 0; i < 16; ++i) {
    int idx = i * 256 + t;
    int r = idx >> 6, c = idx & 63;
    tile[r][c] = f2bf(in[(size_t)(r0 + r) * Cc + c0 + c]);
  }
  __syncthreads();
#pragma unroll
  for (int i = 0; i < 16; ++i) {
    int idx = i * 256 + t;
    int rr = idx >> 6, cc = idx & 63;
    out[(size_t)(c0 + rr) * R + r0 + cc] = tile[cc][rr];
  }
}

// ============ 4-phase 256x256 GEMM: C = A[M][K] * Bt[N][K]^T ==============
// T4 discipline: all 8 stage-issues clustered in phases 0-1 (>=2 phases of
// slack per load); phases 0-2 end with bare s_barrier; ONLY phase 3 ends with
// vmcnt(0)+barrier (drains tile t+1's loads, issued 2-3 phases earlier).
#define GSYNC1 do { __builtin_amdgcn_s_barrier(); \
    asm volatile("s_waitcnt lgkmcnt(0)" ::: "memory"); \
    __builtin_amdgcn_sched_barrier(0); } while (0)
#define PBAR do { __builtin_amdgcn_s_barrier(); } while (0)
#define TBAR do { \
    asm volatile("s_waitcnt vmcnt(0)" ::: "memory"); \
    __builtin_amdgcn_sched_barrier(0); \
    __builtin_amdgcn_s_barrier(); } while (0)

// EPI=1: bf16 C[M][N] + fused RoPE (tile N=256 = one head; pairs (d,d+128)
//        in-tile; sin/cos tables have duplicated halves so index [pos*256+d]).
// EPI=2: f32 C (no rope). EPI=5: fused KV — K half -> kbuf rows WITH RoPE;
// V half -> vtbuf ATTN-TILED (no rope): elem(b,kvh,s,d) =
//   plane*524288 + (s>>5)*8192 + (d>>4)*512 + ((s&31)>>2)*64 + (d&15)*4 + (s&3)
template <int EPI>
__global__ __launch_bounds__(512, 2) void gemm256(const ushort* __restrict__ A,
                                                  const ushort* __restrict__ Bt,
                                                  void* __restrict__ Cout,
                                                  const float* __restrict__ sinT,
                                                  const float* __restrict__ cosT,
                                                  int M, int N, int K) {
  __shared__ alignas(16) char lds[131072];
  const int t = threadIdx.x;
  const int lane = t & 63;
  const int wid = t >> 6;
  const int wm = wid >> 2;   // 0..1
  const int wn = wid & 3;    // 0..3
  const int g = lane >> 4;
  const int lr = lane & 15;
  const int lrow8 = lane >> 3;
  const int lp = (lane & 7) ^ lrow8;  // pre-swizzled staging chunk

  const int nbn = N >> 8;
  const int nwg = (int)gridDim.x;
  const int bid = (int)blockIdx.x;
  const int swz = (bid & 7) * (nwg >> 3) + (bid >> 3);
  const int bm = swz / nbn, bn = swz % nbn;
  const int m0 = bm << 8, n0 = bn << 8;

  f32x4_t acc[8][4] = {};
  const int T = K >> 6;

  auto stageA = [&](int q, int koff, int bufn) {
    int row = (q << 6) + (wid << 3) + lrow8;
    gload16(A + (size_t)(m0 + row) * K + koff + (lp << 3),
            lds + bufn * 32768 + (q << 13) + (wid << 10));
  };
  auto stageB = [&](int q, int koff, int bufn) {
    int row = (q << 6) + (wid << 3) + lrow8;
    gload16(Bt + (size_t)(n0 + row) * K + koff + (lp << 3),
            lds + 65536 + bufn * 32768 + (q << 13) + (wid << 10));
  };

  // prologue: tile 0 -> buf 0
#pragma unroll
  for (int q = 0; q < 4; ++q) { stageA(q, 0, 0); stageB(q, 0, 0); }
  asm volatile("s_waitcnt vmcnt(0)" ::: "memory");
  __builtin_amdgcn_s_barrier();

  for (int tt = 0; tt < T; ++tt) {
    const int bc = tt & 1;
    const int bnx = bc ^ 1;
    const bool st = (tt + 1 < T);
    const int kn = (tt + 1) << 6;
    const char* cA = lds + bc * 32768;
    const char* cB = lds + 65536 + bc * 32768;
    bf16x8_t af[4], bfv[4];

    auto ldA = [&](int i, int mh, int ks) {
      int row = (wm << 7) + (mh << 6) + (i << 4) + lr;
      af[i] = *(const bf16x8_t*)(cA + (row << 7) + (((ks << 6) + (g << 4)) ^ ((row & 7) << 4)));
    };
    auto ldB = [&](int j, int ks) {
      int row = (wn << 6) + (j << 4) + lr;
      bfv[j] = *(const bf16x8_t*)(cB + (row << 7) + (((ks << 6) + (g << 4)) ^ ((row & 7) << 4)));
    };

    // ---- phase 0: mh0, ks0; stage all 4 A-quarters of tile t+1 ----
#pragma unroll
    for (int i = 0; i < 4; ++i) ldA(i, 0, 0);
#pragma unroll
    for (int j = 0; j < 4; ++j) ldB(j, 0);
    if (st) { stageA(0, kn, bnx); stageA(1, kn, bnx); stageA(2, kn, bnx); stageA(3, kn, bnx); }
    GSYNC1;
    __builtin_amdgcn_s_setprio(1);
#pragma unroll
    for (int i = 0; i < 4; ++i)
#pragma unroll
      for (int j = 0; j < 4; ++j)
        acc[i][j] = __builtin_amdgcn_mfma_f32_16x16x32_bf16(af[i], bfv[j], acc[i][j], 0, 0, 0);
    __builtin_amdgcn_s_setprio(0);
    PBAR;

    // ---- phase 1: mh1, ks0; stage all 4 B-quarters of tile t+1 ----
#pragma unroll
    for (int i = 0; i < 4; ++i) ldA(i, 1, 0);
    if (st) { stageB(0, kn, bnx); stageB(1, kn, bnx); stageB(2, kn, bnx); stageB(3, kn, bnx); }
    GSYNC1;
    __builtin_amdgcn_s_setprio(1);
#pragma unroll
    for (int i = 0; i < 4; ++i)
#pragma unroll
      for (int j = 0; j < 4; ++j)
        acc[4 + i][j] = __builtin_amdgcn_mfma_f32_16x16x32_bf16(af[i], bfv[j], acc[4 + i][j], 0, 0, 0);
    __builtin_amdgcn_s_setprio(0);
    PBAR;

    // ---- phase 2: mh0, ks1 ----
#pragma unroll
    for (int i = 0; i < 4; ++i) ldA(i, 0, 1);
#pragma unroll
    for (int j = 0; j < 4; ++j) ldB(j, 1);
    GSYNC1;
    __builtin_amdgcn_s_setprio(1);
#pragma unroll
    for (int i = 0; i < 4; ++i)
#pragma unroll
      for (int j = 0; j < 4; ++j)
        acc[i][j] = __builtin_amdgcn_mfma_f32_16x16x32_bf16(af[i], bfv[j], acc[i][j], 0, 0, 0);
    __builtin_amdgcn_s_setprio(0);
    PBAR;

    // ---- phase 3: mh1, ks1; single per-tile vmem drain ----
#pragma unroll
    for (int i = 0; i < 4; ++i) ldA(i, 1, 1);
    GSYNC1;
    __builtin_amdgcn_s_setprio(1);
#pragma unroll
    for (int i = 0; i < 4; ++i)
#pragma unroll
      for (int j = 0; j < 4; ++j)
        acc[4 + i][j] = __builtin_amdgcn_mfma_f32_16x16x32_bf16(af[i], bfv[j], acc[4 + i][j], 0, 0, 0);
    __builtin_amdgcn_s_setprio(0);
    TBAR;
  }

  // ---- epilogue: stage tile in LDS, then wide (rope-fused) stores ----
  __syncthreads();
  const bool trstage = (EPI == 5) && (n0 >= 2048);
  if (trstage) {
#pragma unroll
    for (int i = 0; i < 8; ++i)
#pragma unroll
      for (int j = 0; j < 4; ++j) {
        int col = (wn << 6) + (j << 4) + lr;
#pragma unroll
        for (int r = 0; r < 4; ++r) {
          int row = (wm << 7) + (i << 4) + (g << 2) + r;
          *(ushort*)(lds + (col << 9) + ((row << 1) ^ ((col & 7) << 4))) = f2bf(acc[i][j][r]);
        }
      }
  } else {
#pragma unroll
    for (int i = 0; i < 8; ++i)
#pragma unroll
      for (int j = 0; j < 4; ++j) {
        int col = (wn << 6) + (j << 4) + lr;
#pragma unroll
        for (int r = 0; r < 4; ++r) {
          int row = (wm << 7) + (i << 4) + (g << 2) + r;
          *(ushort*)(lds + (row << 9) + ((col << 1) ^ ((row & 7) << 4))) = f2bf(acc[i][j][r]);
        }
      }
  }
  __syncthreads();

  if (EPI == 1) {
    ushort* C = (ushort*)Cout;
#pragma unroll
    for (int it = 0; it < 16; ++it) {
      int idx = it * 512 + t;
      int row = idx >> 5, ch = idx & 31;
      uint4 v = *(const uint4*)(lds + (row << 9) + ((ch << 4) ^ ((row & 7) << 4)));
      uint4 p = *(const uint4*)(lds + (row << 9) + (((ch ^ 16) << 4) ^ ((row & 7) << 4)));
      int pos = (m0 + row) & (NS - 1);
      int d0 = ch << 3;
      float4 c0 = *(const float4*)(cosT + (size_t)pos * 256 + d0);
      float4 c1 = *(const float4*)(cosT + (size_t)pos * 256 + d0 + 4);
      float4 s0 = *(const float4*)(sinT + (size_t)pos * 256 + d0);
      float4 s1 = *(const float4*)(sinT + (size_t)pos * 256 + d0 + 4);
      float cs[8] = {c0.x, c0.y, c0.z, c0.w, c1.x, c1.y, c1.z, c1.w};
      float ss[8] = {s0.x, s0.y, s0.z, s0.w, s1.x, s1.y, s1.z, s1.w};
      const float sgn = (ch < 16) ? -1.f : 1.f;
      const ushort* vv = (const ushort*)&v;
      const ushort* pp = (const ushort*)&p;
      ushort o[8];
#pragma unroll
      for (int e = 0; e < 8; ++e)
        o[e] = f2bf(bf2f(vv[e]) * cs[e] + sgn * bf2f(pp[e]) * ss[e]);
      *(uint4*)(C + (size_t)(m0 + row) * N + n0 + (ch << 3)) = *(const uint4*)o;
    }
  } else if (EPI == 5) {
    ushort* C = (ushort*)Cout;
    if (n0 < 2048) {  // K half -> kbuf, WITH RoPE
#pragma unroll
      for (int it = 0; it < 16; ++it) {
        int idx = it * 512 + t;
        int row = idx >> 5, ch = idx & 31;
        uint4 v = *(const uint4*)(lds + (row << 9) + ((ch << 4) ^ ((row & 7) << 4)));
        uint4 p = *(const uint4*)(lds + (row << 9) + (((ch ^ 16) << 4) ^ ((row & 7) << 4)));
        int pos = (m0 + row) & (NS - 1);
        int d0 = ch << 3;
        float4 c0 = *(const float4*)(cosT + (size_t)pos * 256 + d0);
        float4 c1 = *(const float4*)(cosT + (size_t)pos * 256 + d0 + 4);
        float4 s0 = *(const float4*)(sinT + (size_t)pos * 256 + d0);
        float4 s1 = *(const float4*)(sinT + (size_t)pos * 256 + d0 + 4);
        float cs[8] = {c0.x, c0.y, c0.z, c0.w, c1.x, c1.y, c1.z, c1.w};
        float ss[8] = {s0.x, s0.y, s0.z, s0.w, s1.x, s1.y, s1.z, s1.w};
        const float sgn = (ch < 16) ? -1.f : 1.f;
        const ushort* vv = (const ushort*)&v;
        const ushort* pp = (const ushort*)&p;
        ushort o[8];
#pragma unroll
        for (int e = 0; e < 8; ++e)
          o[e] = f2bf(bf2f(vv[e]) * cs[e] + sgn * bf2f(pp[e]) * ss[e]);
        *(uint4*)(C + (size_t)(m0 + row) * 2048 + n0 + (ch << 3)) = *(const uint4*)o;
      }
    } else {
      // V half -> tiled vtbuf (no rope). Fully linear store: elem = base + s*8.
      ushort* vC = C + (size_t)4096 * 2048;
      const int plane = (m0 >> 11) * NKVH + ((n0 - 2048) >> 8);
      ushort* dst = vC + (size_t)plane * ((size_t)NS * DH) + (size_t)((m0 & (NS - 1)) >> 5) * 8192;
#pragma unroll
      for (int it = 0; it < 16; ++it) {
        int s = it * 512 + t;
        int lr2 = s & 7, kq = (s >> 3) & 7, dt_l = (s >> 6) & 15, sb_l = s >> 10;
        int d0 = (dt_l << 4) + (lr2 << 1);   // lds col
        int r0 = (sb_l << 5) + (kq << 2);    // lds row (token)
        uint2 a = *(const uint2*)(lds + (d0 << 9) + ((r0 << 1) ^ ((d0 & 7) << 4)));
        uint2 b2 = *(const uint2*)(lds + ((d0 + 1) << 9) + ((r0 << 1) ^ (((d0 + 1) & 7) << 4)));
        uint4 v; v.x = a.x; v.y = a.y; v.z = b2.x; v.w = b2.y;
        *(uint4*)(dst + (size_t)s * 8) = v;
      }
    }
  } else {
    float* Cf = (float*)Cout;
#pragma unroll
    for (int it = 0; it < 32; ++it) {
      int idx = it * 512 + t;
      int row = idx >> 6, qd = idx & 63;
      ushort4 hv = *(const ushort4*)(lds + (row << 9) + ((qd << 3) ^ ((row & 7) << 4)));
      float4 fv;
      fv.x = bf2f(hv.x); fv.y = bf2f(hv.y); fv.z = bf2f(hv.z); fv.w = bf2f(hv.w);
      *(float4*)(Cf + (size_t)(m0 + row) * N + n0 + (qd << 2)) = fv;
    }
  }
}

// ---------------- flash attention v6: QBLK=64 dbuf + tiled-V + LPT decode --
// (round-15 kernel, measured 167us / FETCH 41MB) grid 1024. xcd=bid&7 ->
// planes {2x,2x+1}; heavy q-blocks dispatch first (LPT). Body = round-8
// structure with tiled-V (linear gload16, bank-bijective PV reads).
__global__ __launch_bounds__(256) void attn_kernel(const ushort* __restrict__ q,
                                                   const ushort* __restrict__ k,
                                                   const ushort* __restrict__ vt,
                                                   ushort* __restrict__ ao) {
  __shared__ alignas(16) char lK[2][16384];
  __shared__ alignas(16) char lV[2][16384];
  const int bid = (int)blockIdx.x;
  const int x = bid & 7;
  const int s_ = bid >> 3;       // 0..127
  const int rnd = s_ >> 5;       // 0..3
  const int c = s_ & 31;
  const int a = c >> 1;
  const int hl = c & 1;
  const int plane = (x << 1) | (rnd & 1);
  int qb;
  if (rnd < 2) qb = 16 + a;          // heavy first (LPT)
  else if (rnd == 2) qb = a;         // light ascending
  else qb = 15 - a;                  // light descending
  const int b = plane >> 3;
  const int kvh = plane & 7;
  const int h = (kvh << 1) | hl;
  const int qb0 = qb << 6;
  const int t = threadIdx.x;
  const int lane = t & 63;
  const int w = t >> 6;
  const int g = lane >> 4;
  const int lr = lane & 15;

  const int qrow = qb0 + (w << 4) + lr;
  bf16x8_t qf[8];
  const ushort* qbase = q + (size_t)(b * NS + qrow) * (NHEADS * DH) + h * DH;
#pragma unroll
  for (int ks = 0; ks < 8; ++ks)
    qf[ks] = *(const bf16x8_t*)(qbase + (ks << 5) + (g << 3));

  float l_r = 0.f;
  f32x4_t oacc[16] = {};

  const int qminw = qb0 + (w << 4);
  const int qmaxw = qminw + 15;
  int t_lo = qb0 - (WIN - 1);
  if (t_lo < 0) t_lo = 0;
  t_lo &= ~31;
  const int t_hi = qb0 + 63;
  const int nt = ((t_hi - t_lo) >> 5) + 1;

  const ushort* kgb = k + (size_t)(b * NS) * (NKVH * DH) + kvh * DH;
  const ushort* vgb = vt + (size_t)(b * NKVH + kvh) * ((size_t)NS * DH);  // tiled plane

  auto stage = [&](int kt, int bi) {
    char* dk = lK[bi];
    char* dv = lV[bi];
    const int sb = kt >> 5;
#pragma unroll
    for (int j = 0; j < 4; ++j) {
      int i = (w << 2) + j;  // 0..15
      // K: issue i stages rows 2i, 2i+1 (1KB); source chunk pre-swizzled.
      int row = (i << 1) + (lane >> 5);
      int ck = (lane & 31) ^ (row & 7);
      gload16(kgb + (size_t)(kt + row) * (NKVH * DH) + (ck << 3), dk + (i << 10));
      // V: tiled layout, fully linear (16KB contiguous per 32-key tile).
      gload16(vgb + (size_t)sb * 8192 + (((i << 6) + lane) << 3), dv + (i << 10));
    }
  };

  int cur = 0;
  stage(t_lo, 0);
  __syncthreads();

  for (int i = 0; i < nt; ++i) {
    const int kt = t_lo + (i << 5);
    if (i + 1 < nt) stage(kt + 32, cur ^ 1);  // async prefetch into other buf
    const char* lk = lK[cur];
    const char* lv = lV[cur];
#pragma unroll
    for (int sub = 0; sub < 2; ++sub) {
      const int key0 = kt + (sub << 4);
      if (key0 > qmaxw) continue;
      if (key0 + 15 < qminw - (WIN - 1)) continue;

      f32x4_t sacc = {};
      __builtin_amdgcn_s_setprio(1);
#pragma unroll
      for (int ks = 0; ks < 8; ++ks) {
        int row = (sub << 4) + lr;
        bf16x8_t kf = *(const bf16x8_t*)(lk + (((row << 9) + (ks << 6) + (g << 4)) ^ ((row & 7) << 4)));
        sacc = __builtin_amdgcn_mfma_f32_16x16x32_bf16(kf, qf[ks], sacc, 0, 0, 0);
      }
      __builtin_amdgcn_s_setprio(0);

      float pvv[4];
      const bool full = (key0 + 15 <= qminw) && (key0 >= qmaxw - (WIN - 1));
      if (full) {
#pragma unroll
        for (int r = 0; r < 4; ++r) { pvv[r] = pexp(sacc[r]); l_r += pvv[r]; }
      } else {
#pragma unroll
        for (int r = 0; r < 4; ++r) {
          int key = key0 + (g << 2) + r;
          bool ok = (key <= qrow) && (qrow - key < WIN);
          pvv[r] = ok ? pexp(sacc[r]) : 0.f;
          l_r += pvv[r];
        }
      }

      s16x4_t pa;
      pa[0] = (short)f2bf(pvv[0]);
      pa[1] = (short)f2bf(pvv[1]);
      pa[2] = (short)f2bf(pvv[2]);
      pa[3] = (short)f2bf(pvv[3]);

      const int kqoff = ((sub << 2) + g) << 7;  // kq*128 bytes
      __builtin_amdgcn_s_setprio(1);
#pragma unroll
      for (int dt = 0; dt < 16; ++dt) {
        s16x4_t vf = *(const s16x4_t*)(lv + (dt << 10) + kqoff + (lr << 3));
        oacc[dt] = mfma_pv(pa, vf, oacc[dt]);
      }
      __builtin_amdgcn_s_setprio(0);
    }
    __syncthreads();  // drains gloads (next tile ready) + all waves done with cur
    cur ^= 1;
  }

  l_r += __shfl_xor(l_r, 16);
  l_r += __shfl_xor(l_r, 32);
  float dn[4];
#pragma unroll
  for (int r = 0; r < 4; ++r)
    dn[r] = 1.0f / __shfl(l_r, (g << 2) + r);

  const int orow0 = b * NS + qb0 + (w << 4) + (g << 2);
#pragma unroll
  for (int dt = 0; dt < 16; ++dt) {
    int col = h * DH + (dt << 4) + lr;
#pragma unroll
    for (int r = 0; r < 4; ++r) {
      ao[(size_t)(orow0 + r) * (NHEADS * DH) + col] = f2bf(oacc[dt][r] * dn[r]);
    }
  }
}

extern "C" void kernel_launch(void* const* d_in, const int* in_sizes, int n_in,
                              void* d_out, int out_size, void* d_ws, size_t ws_size,
                              hipStream_t stream) {
  const float* hs   = (const float*)d_in[0];
  const float* sint = (const float*)d_in[3];
  const float* cost = (const float*)d_in[4];
  const float* Wq = (const float*)d_in[6];
  const float* Wk = (const float*)d_in[7];
  const float* Wv = (const float*)d_in[8];
  const float* Wo = (const float*)d_in[9];

  char* ws = (char*)d_ws;
  size_t off = 0;
  auto alloc = [&](size_t bytes) {
    char* p = ws + off;
    off += (bytes + 255) & ~(size_t)255;
    return p;
  };
  ushort* hsb   = (ushort*)alloc((size_t)4096 * 3584 * 2);  // hs in bf16
  ushort* wT    = (ushort*)alloc((size_t)4096 * 3584 * 2);  // reused weight^T buffer
  ushort* qbuf  = (ushort*)alloc((size_t)4096 * 4096 * 2);
  ushort* kbuf  = (ushort*)alloc((size_t)4096 * 2048 * 2);  // MUST precede vtbuf
  ushort* vtbuf = (ushort*)alloc((size_t)4096 * 2048 * 2);  // = kbuf + 4096*2048 (tiled)
  ushort* aobuf = qbuf;  // alias: attn writes exactly the region only it reads
  if (off > ws_size) return;

  // hs f32 -> bf16
  f32_to_bf16_kernel<<<(4096 * 3584 / 4) / 256, 256, 0, stream>>>(hs, hsb, 4096 * 3584 / 4);

  // fused K+V projection (RoPE fused on K half): Bt = [WkT; WvT] stacked in wT
  transpose_f32_bf16<<<(3584 / 64) * (2048 / 64), 256, 0, stream>>>(Wk, wT, 3584, 2048);
  transpose_f32_bf16<<<(3584 / 64) * (2048 / 64), 256, 0, stream>>>(Wv, wT + (size_t)2048 * 3584, 3584, 2048);
  gemm256<5><<<16 * 16, 512, 0, stream>>>(hsb, wT, kbuf, sint, cost, 4096, 4096, 3584);

  // Q projection (RoPE fused)
  transpose_f32_bf16<<<(3584 / 64) * (4096 / 64), 256, 0, stream>>>(Wq, wT, 3584, 4096);
  gemm256<1><<<16 * 16, 512, 0, stream>>>(hsb, wT, qbuf, sint, cost, 4096, 4096, 3584);

  // attention: QBLK=64, LPT/XCD decode (ao aliases qbuf)
  attn_kernel<<<NB * NHEADS * (NS / 64), 256, 0, stream>>>(qbuf, kbuf, vtbuf, aobuf);

  // output projection, f32 out
  transpose_f32_bf16<<<(4096 / 64) * (3584 / 64), 256, 0, stream>>>(Wo, wT, 4096, 3584);
  gemm256<2><<<16 * 14, 512, 0, stream>>>(aobuf, wT, d_out, nullptr, nullptr, 4096, 3584, 4096);
}

// Round 17
// 533.374 us; speedup vs baseline: 1.5287x; 1.0494x over previous
//
#include <hip/hip_runtime.h>
#include <hip/hip_bf16.h>

typedef __bf16 bf16x8_t __attribute__((ext_vector_type(8)));
typedef __bf16 bf16x4_t __attribute__((ext_vector_type(4)));
typedef short s16x4_t  __attribute__((ext_vector_type(4)));
typedef float f32x4_t  __attribute__((ext_vector_type(4)));

#define NB 2
#define NS 2048
#define NHID 3584
#define NHEADS 16
#define NKVH 8
#define DH 256
#define WIN 1024

__device__ __forceinline__ float bf2f(ushort u) {
  union { unsigned v; float f; } x; x.v = ((unsigned)u) << 16; return x.f;
}
__device__ __forceinline__ ushort f2bf(float f) {
  unsigned x = __builtin_bit_cast(unsigned, f);
  unsigned r = (x + 0x7fffu + ((x >> 16) & 1u)) >> 16;
  return (ushort)r;
}

__device__ __forceinline__ void gload16(const void* g, void* l) {
  __builtin_amdgcn_global_load_lds((const __attribute__((address_space(1))) void*)g,
                                   (__attribute__((address_space(3))) void*)l, 16, 0, 0);
}

__device__ __forceinline__ f32x4_t mfma_pv(s16x4_t a, s16x4_t b, f32x4_t c) {
#if __has_builtin(__builtin_amdgcn_mfma_f32_16x16x16_bf16)
  return __builtin_amdgcn_mfma_f32_16x16x16_bf16(
      __builtin_bit_cast(bf16x4_t, a), __builtin_bit_cast(bf16x4_t, b), c, 0, 0, 0);
#else
  return __builtin_amdgcn_mfma_f32_16x16x16bf16_1k(a, b, c, 0, 0, 0);
#endif
}

__device__ __forceinline__ float fexp2(float x) {
#if __has_builtin(__builtin_amdgcn_exp2f)
  return __builtin_amdgcn_exp2f(x);
#else
  return exp2f(x);
#endif
}
__device__ __forceinline__ float frcp(float x) {
#if __has_builtin(__builtin_amdgcn_rcpf)
  return __builtin_amdgcn_rcpf(x);
#else
  return 1.0f / x;
#endif
}

// softcap softmax weight, uniformly scaled by e^-25 (cancels in l-normalize):
// p' = exp(25 - 100/(e^{2x}+1)), x = s/800  ==> exp2 form, clamp-free
// (s->+inf: e=inf, rcp=0, p=e^25; s->-inf: e=0, rcp=1, p=e^-75 -- bf16-normal)
__device__ __forceinline__ float pexp(float s) {
  float e = fexp2(s * 0.0036067376f);          // 2^(C1*s) = e^{2x}
  float r = frcp(e + 1.0f);
  return fexp2(36.067376f - 144.2695041f * r); // 2^(C2 - C3*r)
}

// ---------------- f32 -> bf16 elementwise convert (x4 vectorized) ---------
__global__ __launch_bounds__(256) void f32_to_bf16_kernel(const float* __restrict__ in,
                                                          ushort* __restrict__ out, int n4) {
  int i = (int)blockIdx.x * 256 + (int)threadIdx.x;
  if (i < n4) {
    float4 v = ((const float4*)in)[i];
    ushort4 o;
    o.x = f2bf(v.x); o.y = f2bf(v.y); o.z = f2bf(v.z); o.w = f2bf(v.w);
    ((ushort4*)out)[i] = o;
  }
}

// ------------- transpose+convert: f32 in[R][C] -> bf16 out[C][R] ----------
__global__ __launch_bounds__(256) void transpose_f32_bf16(const float* __restrict__ in,
                                                          ushort* __restrict__ out,
                                                          int R, int Cc) {
  __shared__ ushort tile[64][72];
  const int t = threadIdx.x;
  const int ct = Cc >> 6;
  const int by = blockIdx.x / ct;
  const int bx = blockIdx.x % ct;
  const int r0 = by << 6, c0 = bx << 6;
#pragma unroll
  for (int i = 0; i < 16; ++i) {
    int idx = i * 256 + t;
    int r = idx >> 6, c = idx & 63;
    tile[r][c] = f2bf(in[(size_t)(r0 + r) * Cc + c0 + c]);
  }
  __syncthreads();
#pragma unroll
  for (int i = 0; i < 16; ++i) {
    int idx = i * 256 + t;
    int rr = idx >> 6, cc = idx & 63;
    out[(size_t)(c0 + rr) * R + r0 + cc] = tile[cc][rr];
  }
}

// ============ 4-phase 256x256 GEMM with ds-read pipelining ================
// Fragment ds_reads for phase p+1 are issued BEFORE phase p's MFMA cluster
// (double fragment sets afA/afB, bfvA/bfvB); no explicit lgkmcnt(0) -- the
// compiler inserts counted waits from the register dependence, so each MFMA
// waits only on reads issued a full phase earlier. Stages clustered ph0/ph1;
// single vmcnt(0) drain per tile at phase 3 (TBAR).
#define TBAR do { \
    asm volatile("s_waitcnt vmcnt(0)" ::: "memory"); \
    __builtin_amdgcn_sched_barrier(0); \
    __builtin_amdgcn_s_barrier(); } while (0)

// EPI=1: bf16 C[M][N] + fused RoPE. EPI=2: f32 C. EPI=5: fused KV — K half
// WITH RoPE -> kbuf; V half -> vtbuf ATTN-TILED: elem(b,kvh,s,d) =
//   plane*524288 + (s>>5)*8192 + (d>>4)*512 + ((s&31)>>2)*64 + (d&15)*4 + (s&3)
template <int EPI>
__global__ __launch_bounds__(512, 2) void gemm256(const ushort* __restrict__ A,
                                                  const ushort* __restrict__ Bt,
                                                  void* __restrict__ Cout,
                                                  const float* __restrict__ sinT,
                                                  const float* __restrict__ cosT,
                                                  int M, int N, int K) {
  __shared__ alignas(16) char lds[131072];
  const int t = threadIdx.x;
  const int lane = t & 63;
  const int wid = t >> 6;
  const int wm = wid >> 2;   // 0..1
  const int wn = wid & 3;    // 0..3
  const int g = lane >> 4;
  const int lr = lane & 15;
  const int lrow8 = lane >> 3;
  const int lp = (lane & 7) ^ lrow8;  // pre-swizzled staging chunk

  const int nbn = N >> 8;
  const int nwg = (int)gridDim.x;
  const int bid = (int)blockIdx.x;
  const int swz = (bid & 7) * (nwg >> 3) + (bid >> 3);
  const int bm = swz / nbn, bn = swz % nbn;
  const int m0 = bm << 8, n0 = bn << 8;

  f32x4_t acc[8][4] = {};
  const int T = K >> 6;

  auto stageA = [&](int q, int koff, int bufn) {
    int row = (q << 6) + (wid << 3) + lrow8;
    gload16(A + (size_t)(m0 + row) * K + koff + (lp << 3),
            lds + bufn * 32768 + (q << 13) + (wid << 10));
  };
  auto stageB = [&](int q, int koff, int bufn) {
    int row = (q << 6) + (wid << 3) + lrow8;
    gload16(Bt + (size_t)(n0 + row) * K + koff + (lp << 3),
            lds + 65536 + bufn * 32768 + (q << 13) + (wid << 10));
  };
  auto ldAfrag = [&](bf16x8_t* dst, const char* cA, int mh, int ks) {
#pragma unroll
    for (int i = 0; i < 4; ++i) {
      int row = (wm << 7) + (mh << 6) + (i << 4) + lr;
      dst[i] = *(const bf16x8_t*)(cA + (row << 7) + (((ks << 6) + (g << 4)) ^ ((row & 7) << 4)));
    }
  };
  auto ldBfrag = [&](bf16x8_t* dst, const char* cB, int ks) {
#pragma unroll
    for (int j = 0; j < 4; ++j) {
      int row = (wn << 6) + (j << 4) + lr;
      dst[j] = *(const bf16x8_t*)(cB + (row << 7) + (((ks << 6) + (g << 4)) ^ ((row & 7) << 4)));
    }
  };

  // prologue: tile 0 -> buf 0
#pragma unroll
  for (int q = 0; q < 4; ++q) { stageA(q, 0, 0); stageB(q, 0, 0); }
  asm volatile("s_waitcnt vmcnt(0)" ::: "memory");
  __builtin_amdgcn_s_barrier();

  bf16x8_t afA[4], afB[4], bfvA[4], bfvB[4];
  ldAfrag(afA, lds, 0, 0);
  ldBfrag(bfvA, lds + 65536, 0);

  for (int tt = 0; tt < T; ++tt) {
    const int bc = tt & 1;
    const int bnx = bc ^ 1;
    const bool st = (tt + 1 < T);
    const int kn = (tt + 1) << 6;
    const char* cA = lds + bc * 32768;
    const char* cB = lds + 65536 + bc * 32768;

    // ---- phase 0: MFMA(afA,bfvA); ds-prefetch afB=(mh1,ks0); stage A x4 ----
    ldAfrag(afB, cA, 1, 0);
    if (st) { stageA(0, kn, bnx); stageA(1, kn, bnx); stageA(2, kn, bnx); stageA(3, kn, bnx); }
    __builtin_amdgcn_s_barrier();
    __builtin_amdgcn_s_setprio(1);
#pragma unroll
    for (int i = 0; i < 4; ++i)
#pragma unroll
      for (int j = 0; j < 4; ++j)
        acc[i][j] = __builtin_amdgcn_mfma_f32_16x16x32_bf16(afA[i], bfvA[j], acc[i][j], 0, 0, 0);
    __builtin_amdgcn_s_setprio(0);
    __builtin_amdgcn_s_barrier();

    // ---- phase 1: MFMA(afB,bfvA); ds-prefetch afA=(mh0,ks1), bfvB=(ks1); stage B x4 ----
    ldAfrag(afA, cA, 0, 1);
    ldBfrag(bfvB, cB, 1);
    if (st) { stageB(0, kn, bnx); stageB(1, kn, bnx); stageB(2, kn, bnx); stageB(3, kn, bnx); }
    __builtin_amdgcn_s_barrier();
    __builtin_amdgcn_s_setprio(1);
#pragma unroll
    for (int i = 0; i < 4; ++i)
#pragma unroll
      for (int j = 0; j < 4; ++j)
        acc[4 + i][j] = __builtin_amdgcn_mfma_f32_16x16x32_bf16(afB[i], bfvA[j], acc[4 + i][j], 0, 0, 0);
    __builtin_amdgcn_s_setprio(0);
    __builtin_amdgcn_s_barrier();

    // ---- phase 2: MFMA(afA,bfvB); ds-prefetch afB=(mh1,ks1) ----
    ldAfrag(afB, cA, 1, 1);
    __builtin_amdgcn_s_barrier();
    __builtin_amdgcn_s_setprio(1);
#pragma unroll
    for (int i = 0; i < 4; ++i)
#pragma unroll
      for (int j = 0; j < 4; ++j)
        acc[i][j] = __builtin_amdgcn_mfma_f32_16x16x32_bf16(afA[i], bfvB[j], acc[i][j], 0, 0, 0);
    __builtin_amdgcn_s_setprio(0);
    __builtin_amdgcn_s_barrier();

    // ---- phase 3: MFMA(afB,bfvB); single per-tile vmem drain ----
    __builtin_amdgcn_s_setprio(1);
#pragma unroll
    for (int i = 0; i < 4; ++i)
#pragma unroll
      for (int j = 0; j < 4; ++j)
        acc[4 + i][j] = __builtin_amdgcn_mfma_f32_16x16x32_bf16(afB[i], bfvB[j], acc[4 + i][j], 0, 0, 0);
    __builtin_amdgcn_s_setprio(0);
    TBAR;
    if (st) {  // first fragments of next tile from the freshly-drained buffer
      ldAfrag(afA, lds + bnx * 32768, 0, 0);
      ldBfrag(bfvA, lds + 65536 + bnx * 32768, 0);
    }
  }

  // ---- epilogue: stage tile in LDS, then wide (rope-fused) stores ----
  __syncthreads();
  const bool trstage = (EPI == 5) && (n0 >= 2048);
  if (trstage) {
#pragma unroll
    for (int i = 0; i < 8; ++i)
#pragma unroll
      for (int j = 0; j < 4; ++j) {
        int col = (wn << 6) + (j << 4) + lr;
#pragma unroll
        for (int r = 0; r < 4; ++r) {
          int row = (wm << 7) + (i << 4) + (g << 2) + r;
          *(ushort*)(lds + (col << 9) + ((row << 1) ^ ((col & 7) << 4))) = f2bf(acc[i][j][r]);
        }
      }
  } else {
#pragma unroll
    for (int i = 0; i < 8; ++i)
#pragma unroll
      for (int j = 0; j < 4; ++j) {
        int col = (wn << 6) + (j << 4) + lr;
#pragma unroll
        for (int r = 0; r < 4; ++r) {
          int row = (wm << 7) + (i << 4) + (g << 2) + r;
          *(ushort*)(lds + (row << 9) + ((col << 1) ^ ((row & 7) << 4))) = f2bf(acc[i][j][r]);
        }
      }
  }
  __syncthreads();

  if (EPI == 1) {
    ushort* C = (ushort*)Cout;
#pragma unroll
    for (int it = 0; it < 16; ++it) {
      int idx = it * 512 + t;
      int row = idx >> 5, ch = idx & 31;
      uint4 v = *(const uint4*)(lds + (row << 9) + ((ch << 4) ^ ((row & 7) << 4)));
      uint4 p = *(const uint4*)(lds + (row << 9) + (((ch ^ 16) << 4) ^ ((row & 7) << 4)));
      int pos = (m0 + row) & (NS - 1);
      int d0 = ch << 3;
      float4 c0 = *(const float4*)(cosT + (size_t)pos * 256 + d0);
      float4 c1 = *(const float4*)(cosT + (size_t)pos * 256 + d0 + 4);
      float4 s0 = *(const float4*)(sinT + (size_t)pos * 256 + d0);
      float4 s1 = *(const float4*)(sinT + (size_t)pos * 256 + d0 + 4);
      float cs[8] = {c0.x, c0.y, c0.z, c0.w, c1.x, c1.y, c1.z, c1.w};
      float ss[8] = {s0.x, s0.y, s0.z, s0.w, s1.x, s1.y, s1.z, s1.w};
      const float sgn = (ch < 16) ? -1.f : 1.f;
      const ushort* vv = (const ushort*)&v;
      const ushort* pp = (const ushort*)&p;
      ushort o[8];
#pragma unroll
      for (int e = 0; e < 8; ++e)
        o[e] = f2bf(bf2f(vv[e]) * cs[e] + sgn * bf2f(pp[e]) * ss[e]);
      *(uint4*)(C + (size_t)(m0 + row) * N + n0 + (ch << 3)) = *(const uint4*)o;
    }
  } else if (EPI == 5) {
    ushort* C = (ushort*)Cout;
    if (n0 < 2048) {  // K half -> kbuf, WITH RoPE
#pragma unroll
      for (int it = 0; it < 16; ++it) {
        int idx = it * 512 + t;
        int row = idx >> 5, ch = idx & 31;
        uint4 v = *(const uint4*)(lds + (row << 9) + ((ch << 4) ^ ((row & 7) << 4)));
        uint4 p = *(const uint4*)(lds + (row << 9) + (((ch ^ 16) << 4) ^ ((row & 7) << 4)));
        int pos = (m0 + row) & (NS - 1);
        int d0 = ch << 3;
        float4 c0 = *(const float4*)(cosT + (size_t)pos * 256 + d0);
        float4 c1 = *(const float4*)(cosT + (size_t)pos * 256 + d0 + 4);
        float4 s0 = *(const float4*)(sinT + (size_t)pos * 256 + d0);
        float4 s1 = *(const float4*)(sinT + (size_t)pos * 256 + d0 + 4);
        float cs[8] = {c0.x, c0.y, c0.z, c0.w, c1.x, c1.y, c1.z, c1.w};
        float ss[8] = {s0.x, s0.y, s0.z, s0.w, s1.x, s1.y, s1.z, s1.w};
        const float sgn = (ch < 16) ? -1.f : 1.f;
        const ushort* vv = (const ushort*)&v;
        const ushort* pp = (const ushort*)&p;
        ushort o[8];
#pragma unroll
        for (int e = 0; e < 8; ++e)
          o[e] = f2bf(bf2f(vv[e]) * cs[e] + sgn * bf2f(pp[e]) * ss[e]);
        *(uint4*)(C + (size_t)(m0 + row) * 2048 + n0 + (ch << 3)) = *(const uint4*)o;
      }
    } else {
      // V half -> tiled vtbuf (no rope). Fully linear store: elem = base + s*8.
      ushort* vC = C + (size_t)4096 * 2048;
      const int plane = (m0 >> 11) * NKVH + ((n0 - 2048) >> 8);
      ushort* dst = vC + (size_t)plane * ((size_t)NS * DH) + (size_t)((m0 & (NS - 1)) >> 5) * 8192;
#pragma unroll
      for (int it = 0; it < 16; ++it) {
        int s = it * 512 + t;
        int lr2 = s & 7, kq = (s >> 3) & 7, dt_l = (s >> 6) & 15, sb_l = s >> 10;
        int d0 = (dt_l << 4) + (lr2 << 1);   // lds col
        int r0 = (sb_l << 5) + (kq << 2);    // lds row (token)
        uint2 a = *(const uint2*)(lds + (d0 << 9) + ((r0 << 1) ^ ((d0 & 7) << 4)));
        uint2 b2 = *(const uint2*)(lds + ((d0 + 1) << 9) + ((r0 << 1) ^ (((d0 + 1) & 7) << 4)));
        uint4 v; v.x = a.x; v.y = a.y; v.z = b2.x; v.w = b2.y;
        *(uint4*)(dst + (size_t)s * 8) = v;
      }
    }
  } else {
    float* Cf = (float*)Cout;
#pragma unroll
    for (int it = 0; it < 32; ++it) {
      int idx = it * 512 + t;
      int row = idx >> 6, qd = idx & 63;
      ushort4 hv = *(const ushort4*)(lds + (row << 9) + ((qd << 3) ^ ((row & 7) << 4)));
      float4 fv;
      fv.x = bf2f(hv.x); fv.y = bf2f(hv.y); fv.z = bf2f(hv.z); fv.w = bf2f(hv.w);
      *(float4*)(Cf + (size_t)(m0 + row) * N + n0 + (qd << 2)) = fv;
    }
  }
}

// ---------------- flash attention v6.1: v6 + exp2 softmax ------------------
// (v6 measured 167us / FETCH 41MB) grid 1024. xcd=bid&7 -> planes {2x,2x+1};
// heavy q-blocks dispatch first (LPT). Tiled-V (linear gload16, bank-bijective
// PV reads). Softcap weight via 2x v_exp + v_rcp (uniform e^-25 scale cancels).
__global__ __launch_bounds__(256) void attn_kernel(const ushort* __restrict__ q,
                                                   const ushort* __restrict__ k,
                                                   const ushort* __restrict__ vt,
                                                   ushort* __restrict__ ao) {
  __shared__ alignas(16) char lK[2][16384];
  __shared__ alignas(16) char lV[2][16384];
  const int bid = (int)blockIdx.x;
  const int x = bid & 7;
  const int s_ = bid >> 3;       // 0..127
  const int rnd = s_ >> 5;       // 0..3
  const int c = s_ & 31;
  const int a = c >> 1;
  const int hl = c & 1;
  const int plane = (x << 1) | (rnd & 1);
  int qb;
  if (rnd < 2) qb = 16 + a;          // heavy first (LPT)
  else if (rnd == 2) qb = a;         // light ascending
  else qb = 15 - a;                  // light descending
  const int b = plane >> 3;
  const int kvh = plane & 7;
  const int h = (kvh << 1) | hl;
  const int qb0 = qb << 6;
  const int t = threadIdx.x;
  const int lane = t & 63;
  const int w = t >> 6;
  const int g = lane >> 4;
  const int lr = lane & 15;

  const int qrow = qb0 + (w << 4) + lr;
  bf16x8_t qf[8];
  const ushort* qbase = q + (size_t)(b * NS + qrow) * (NHEADS * DH) + h * DH;
#pragma unroll
  for (int ks = 0; ks < 8; ++ks)
    qf[ks] = *(const bf16x8_t*)(qbase + (ks << 5) + (g << 3));

  float l_r = 0.f;
  f32x4_t oacc[16] = {};

  const int qminw = qb0 + (w << 4);
  const int qmaxw = qminw + 15;
  int t_lo = qb0 - (WIN - 1);
  if (t_lo < 0) t_lo = 0;
  t_lo &= ~31;
  const int t_hi = qb0 + 63;
  const int nt = ((t_hi - t_lo) >> 5) + 1;

  const ushort* kgb = k + (size_t)(b * NS) * (NKVH * DH) + kvh * DH;
  const ushort* vgb = vt + (size_t)(b * NKVH + kvh) * ((size_t)NS * DH);  // tiled plane

  auto stage = [&](int kt, int bi) {
    char* dk = lK[bi];
    char* dv = lV[bi];
    const int sb = kt >> 5;
#pragma unroll
    for (int j = 0; j < 4; ++j) {
      int i = (w << 2) + j;  // 0..15
      int row = (i << 1) + (lane >> 5);
      int ck = (lane & 31) ^ (row & 7);
      gload16(kgb + (size_t)(kt + row) * (NKVH * DH) + (ck << 3), dk + (i << 10));
      gload16(vgb + (size_t)sb * 8192 + (((i << 6) + lane) << 3), dv + (i << 10));
    }
  };

  int cur = 0;
  stage(t_lo, 0);
  __syncthreads();

  for (int i = 0; i < nt; ++i) {
    const int kt = t_lo + (i << 5);
    if (i + 1 < nt) stage(kt + 32, cur ^ 1);  // async prefetch into other buf
    const char* lk = lK[cur];
    const char* lv = lV[cur];
#pragma unroll
    for (int sub = 0; sub < 2; ++sub) {
      const int key0 = kt + (sub << 4);
      if (key0 > qmaxw) continue;
      if (key0 + 15 < qminw - (WIN - 1)) continue;

      f32x4_t sacc = {};
      __builtin_amdgcn_s_setprio(1);
#pragma unroll
      for (int ks = 0; ks < 8; ++ks) {
        int row = (sub << 4) + lr;
        bf16x8_t kf = *(const bf16x8_t*)(lk + (((row << 9) + (ks << 6) + (g << 4)) ^ ((row & 7) << 4)));
        sacc = __builtin_amdgcn_mfma_f32_16x16x32_bf16(kf, qf[ks], sacc, 0, 0, 0);
      }
      __builtin_amdgcn_s_setprio(0);

      float pvv[4];
      const bool full = (key0 + 15 <= qminw) && (key0 >= qmaxw - (WIN - 1));
      if (full) {
#pragma unroll
        for (int r = 0; r < 4; ++r) { pvv[r] = pexp(sacc[r]); l_r += pvv[r]; }
      } else {
#pragma unroll
        for (int r = 0; r < 4; ++r) {
          int key = key0 + (g << 2) + r;
          bool ok = (key <= qrow) && (qrow - key < WIN);
          pvv[r] = ok ? pexp(sacc[r]) : 0.f;
          l_r += pvv[r];
        }
      }

      s16x4_t pa;  // truncating f32->bf16 (bias <=0.4%, inside threshold)
      pa[0] = (short)(ushort)(__builtin_bit_cast(unsigned, pvv[0]) >> 16);
      pa[1] = (short)(ushort)(__builtin_bit_cast(unsigned, pvv[1]) >> 16);
      pa[2] = (short)(ushort)(__builtin_bit_cast(unsigned, pvv[2]) >> 16);
      pa[3] = (short)(ushort)(__builtin_bit_cast(unsigned, pvv[3]) >> 16);

      const int kqoff = ((sub << 2) + g) << 7;  // kq*128 bytes
      __builtin_amdgcn_s_setprio(1);
#pragma unroll
      for (int dt = 0; dt < 16; ++dt) {
        s16x4_t vf = *(const s16x4_t*)(lv + (dt << 10) + kqoff + (lr << 3));
        oacc[dt] = mfma_pv(pa, vf, oacc[dt]);
      }
      __builtin_amdgcn_s_setprio(0);
    }
    __syncthreads();  // drains gloads (next tile ready) + all waves done with cur
    cur ^= 1;
  }

  l_r += __shfl_xor(l_r, 16);
  l_r += __shfl_xor(l_r, 32);
  float dn[4];
#pragma unroll
  for (int r = 0; r < 4; ++r)
    dn[r] = 1.0f / __shfl(l_r, (g << 2) + r);

  const int orow0 = b * NS + qb0 + (w << 4) + (g << 2);
#pragma unroll
  for (int dt = 0; dt < 16; ++dt) {
    int col = h * DH + (dt << 4) + lr;
#pragma unroll
    for (int r = 0; r < 4; ++r) {
      ao[(size_t)(orow0 + r) * (NHEADS * DH) + col] = f2bf(oacc[dt][r] * dn[r]);
    }
  }
}

extern "C" void kernel_launch(void* const* d_in, const int* in_sizes, int n_in,
                              void* d_out, int out_size, void* d_ws, size_t ws_size,
                              hipStream_t stream) {
  const float* hs   = (const float*)d_in[0];
  const float* sint = (const float*)d_in[3];
  const float* cost = (const float*)d_in[4];
  const float* Wq = (const float*)d_in[6];
  const float* Wk = (const float*)d_in[7];
  const float* Wv = (const float*)d_in[8];
  const float* Wo = (const float*)d_in[9];

  char* ws = (char*)d_ws;
  size_t off = 0;
  auto alloc = [&](size_t bytes) {
    char* p = ws + off;
    off += (bytes + 255) & ~(size_t)255;
    return p;
  };
  ushort* hsb   = (ushort*)alloc((size_t)4096 * 3584 * 2);  // hs in bf16
  ushort* wT    = (ushort*)alloc((size_t)4096 * 3584 * 2);  // reused weight^T buffer
  ushort* qbuf  = (ushort*)alloc((size_t)4096 * 4096 * 2);
  ushort* kbuf  = (ushort*)alloc((size_t)4096 * 2048 * 2);  // MUST precede vtbuf
  ushort* vtbuf = (ushort*)alloc((size_t)4096 * 2048 * 2);  // = kbuf + 4096*2048 (tiled)
  ushort* aobuf = qbuf;  // alias: attn writes exactly the region only it reads
  if (off > ws_size) return;

  // hs f32 -> bf16
  f32_to_bf16_kernel<<<(4096 * 3584 / 4) / 256, 256, 0, stream>>>(hs, hsb, 4096 * 3584 / 4);

  // fused K+V projection (RoPE fused on K half): Bt = [WkT; WvT] stacked in wT
  transpose_f32_bf16<<<(3584 / 64) * (2048 / 64), 256, 0, stream>>>(Wk, wT, 3584, 2048);
  transpose_f32_bf16<<<(3584 / 64) * (2048 / 64), 256, 0, stream>>>(Wv, wT + (size_t)2048 * 3584, 3584, 2048);
  gemm256<5><<<16 * 16, 512, 0, stream>>>(hsb, wT, kbuf, sint, cost, 4096, 4096, 3584);

  // Q projection (RoPE fused)
  transpose_f32_bf16<<<(3584 / 64) * (4096 / 64), 256, 0, stream>>>(Wq, wT, 3584, 4096);
  gemm256<1><<<16 * 16, 512, 0, stream>>>(hsb, wT, qbuf, sint, cost, 4096, 4096, 3584);

  // attention: QBLK=64, LPT/XCD decode (ao aliases qbuf)
  attn_kernel<<<NB * NHEADS * (NS / 64), 256, 0, stream>>>(qbuf, kbuf, vtbuf, aobuf);

  // output projection, f32 out
  transpose_f32_bf16<<<(4096 / 64) * (3584 / 64), 256, 0, stream>>>(Wo, wT, 4096, 3584);
  gemm256<2><<<16 * 14, 512, 0, stream>>>(aobuf, wT, d_out, nullptr, nullptr, 4096, 3584, 4096);
}

// Round 18
// 517.602 us; speedup vs baseline: 1.5753x; 1.0305x over previous
//
#include <hip/hip_runtime.h>
#include <hip/hip_bf16.h>

typedef __bf16 bf16x8_t __attribute__((ext_vector_type(8)));
typedef __bf16 bf16x4_t __attribute__((ext_vector_type(4)));
typedef short s16x4_t  __attribute__((ext_vector_type(4)));
typedef float f32x4_t  __attribute__((ext_vector_type(4)));

#define NB 2
#define NS 2048
#define NHID 3584
#define NHEADS 16
#define NKVH 8
#define DH 256
#define WIN 1024

__device__ __forceinline__ float bf2f(ushort u) {
  union { unsigned v; float f; } x; x.v = ((unsigned)u) << 16; return x.f;
}
__device__ __forceinline__ ushort f2bf(float f) {
  unsigned x = __builtin_bit_cast(unsigned, f);
  unsigned r = (x + 0x7fffu + ((x >> 16) & 1u)) >> 16;
  return (ushort)r;
}

__device__ __forceinline__ void gload16(const void* g, void* l) {
  __builtin_amdgcn_global_load_lds((const __attribute__((address_space(1))) void*)g,
                                   (__attribute__((address_space(3))) void*)l, 16, 0, 0);
}

__device__ __forceinline__ f32x4_t mfma_pv(s16x4_t a, s16x4_t b, f32x4_t c) {
#if __has_builtin(__builtin_amdgcn_mfma_f32_16x16x16_bf16)
  return __builtin_amdgcn_mfma_f32_16x16x16_bf16(
      __builtin_bit_cast(bf16x4_t, a), __builtin_bit_cast(bf16x4_t, b), c, 0, 0, 0);
#else
  return __builtin_amdgcn_mfma_f32_16x16x16bf16_1k(a, b, c, 0, 0, 0);
#endif
}

__device__ __forceinline__ float fexp2(float x) {
#if __has_builtin(__builtin_amdgcn_exp2f)
  return __builtin_amdgcn_exp2f(x);
#else
  return exp2f(x);
#endif
}
__device__ __forceinline__ float frcp(float x) {
#if __has_builtin(__builtin_amdgcn_rcpf)
  return __builtin_amdgcn_rcpf(x);
#else
  return 1.0f / x;
#endif
}

// softcap softmax weight, uniformly scaled by e^-25 (cancels in l-normalize):
// p' = exp(25 - 100/(e^{2x}+1)), x = s/800  ==> exp2 form, clamp-free
__device__ __forceinline__ float pexp(float s) {
  float e = fexp2(s * 0.0036067376f);
  float r = frcp(e + 1.0f);
  return fexp2(36.067376f - 144.2695041f * r);
}

// ---------------- f32 -> bf16 elementwise convert (x4 vectorized) ---------
__global__ __launch_bounds__(256) void f32_to_bf16_kernel(const float* __restrict__ in,
                                                          ushort* __restrict__ out, int n4) {
  int i = (int)blockIdx.x * 256 + (int)threadIdx.x;
  if (i < n4) {
    float4 v = ((const float4*)in)[i];
    ushort4 o;
    o.x = f2bf(v.x); o.y = f2bf(v.y); o.z = f2bf(v.z); o.w = f2bf(v.w);
    ((ushort4*)out)[i] = o;
  }
}

// ------------- transpose+convert: f32 in[R][C] -> bf16 out[C][R] ----------
__global__ __launch_bounds__(256) void transpose_f32_bf16(const float* __restrict__ in,
                                                          ushort* __restrict__ out,
                                                          int R, int Cc) {
  __shared__ ushort tile[64][72];
  const int t = threadIdx.x;
  const int ct = Cc >> 6;
  const int by = blockIdx.x / ct;
  const int bx = blockIdx.x % ct;
  const int r0 = by << 6, c0 = bx << 6;
#pragma unroll
  for (int i = 0; i < 16; ++i) {
    int idx = i * 256 + t;
    int r = idx >> 6, c = idx & 63;
    tile[r][c] = f2bf(in[(size_t)(r0 + r) * Cc + c0 + c]);
  }
  __syncthreads();
#pragma unroll
  for (int i = 0; i < 16; ++i) {
    int idx = i * 256 + t;
    int rr = idx >> 6, cc = idx & 63;
    out[(size_t)(c0 + rr) * R + r0 + cc] = tile[cc][rr];
  }
}

// ============ 256x256 GEMM, single-barrier K-loop =========================
// Hazard audit: stages write buf^1 while all ds_reads target buf (disjoint);
// every ds_read destination is consumed by an MFMA before TBAR, so lgkm has
// fully retired block-wide at the single vmcnt(0)+s_barrier per K-tile.
// Inter-phase barriers DELETED; fragment prefetch rotation gives each MFMA a
// full phase of ds-read slack via compiler-counted lgkm waits.
#define TBAR do { \
    asm volatile("s_waitcnt vmcnt(0)" ::: "memory"); \
    __builtin_amdgcn_sched_barrier(0); \
    __builtin_amdgcn_s_barrier(); } while (0)

// EPI=1: bf16 C[M][N] + fused RoPE. EPI=2: f32 C. EPI=5: fused KV — K half
// WITH RoPE -> kbuf; V half -> vtbuf ATTN-TILED: elem(b,kvh,s,d) =
//   plane*524288 + (s>>5)*8192 + (d>>4)*512 + ((s&31)>>2)*64 + (d&15)*4 + (s&3)
template <int EPI>
__global__ __launch_bounds__(512, 2) void gemm256(const ushort* __restrict__ A,
                                                  const ushort* __restrict__ Bt,
                                                  void* __restrict__ Cout,
                                                  const float* __restrict__ sinT,
                                                  const float* __restrict__ cosT,
                                                  int M, int N, int K) {
  __shared__ alignas(16) char lds[131072];
  const int t = threadIdx.x;
  const int lane = t & 63;
  const int wid = t >> 6;
  const int wm = wid >> 2;   // 0..1
  const int wn = wid & 3;    // 0..3
  const int g = lane >> 4;
  const int lr = lane & 15;
  const int lrow8 = lane >> 3;
  const int lp = (lane & 7) ^ lrow8;  // pre-swizzled staging chunk

  const int nbn = N >> 8;
  const int nwg = (int)gridDim.x;
  const int bid = (int)blockIdx.x;
  const int swz = (bid & 7) * (nwg >> 3) + (bid >> 3);
  const int bm = swz / nbn, bn = swz % nbn;
  const int m0 = bm << 8, n0 = bn << 8;

  f32x4_t acc[8][4] = {};
  const int T = K >> 6;

  auto stageA = [&](int q, int koff, int bufn) {
    int row = (q << 6) + (wid << 3) + lrow8;
    gload16(A + (size_t)(m0 + row) * K + koff + (lp << 3),
            lds + bufn * 32768 + (q << 13) + (wid << 10));
  };
  auto stageB = [&](int q, int koff, int bufn) {
    int row = (q << 6) + (wid << 3) + lrow8;
    gload16(Bt + (size_t)(n0 + row) * K + koff + (lp << 3),
            lds + 65536 + bufn * 32768 + (q << 13) + (wid << 10));
  };
  auto ldAfrag = [&](bf16x8_t* dst, const char* cA, int mh, int ks) {
#pragma unroll
    for (int i = 0; i < 4; ++i) {
      int row = (wm << 7) + (mh << 6) + (i << 4) + lr;
      dst[i] = *(const bf16x8_t*)(cA + (row << 7) + (((ks << 6) + (g << 4)) ^ ((row & 7) << 4)));
    }
  };
  auto ldBfrag = [&](bf16x8_t* dst, const char* cB, int ks) {
#pragma unroll
    for (int j = 0; j < 4; ++j) {
      int row = (wn << 6) + (j << 4) + lr;
      dst[j] = *(const bf16x8_t*)(cB + (row << 7) + (((ks << 6) + (g << 4)) ^ ((row & 7) << 4)));
    }
  };

  // prologue: tile 0 -> buf 0
#pragma unroll
  for (int q = 0; q < 4; ++q) { stageA(q, 0, 0); stageB(q, 0, 0); }
  asm volatile("s_waitcnt vmcnt(0)" ::: "memory");
  __builtin_amdgcn_s_barrier();

  bf16x8_t afA[4], afB[4], bfvA[4], bfvB[4];
  ldAfrag(afA, lds, 0, 0);
  ldBfrag(bfvA, lds + 65536, 0);

  for (int tt = 0; tt < T; ++tt) {
    const int bc = tt & 1;
    const int bnx = bc ^ 1;
    const bool st = (tt + 1 < T);
    const int kn = (tt + 1) << 6;
    const char* cA = lds + bc * 32768;
    const char* cB = lds + 65536 + bc * 32768;

    // ---- phase 0: MFMA(afA,bfvA); prefetch afB=(mh1,ks0); stage A x4 ----
    ldAfrag(afB, cA, 1, 0);
    if (st) { stageA(0, kn, bnx); stageA(1, kn, bnx); stageA(2, kn, bnx); stageA(3, kn, bnx); }
    __builtin_amdgcn_s_setprio(1);
#pragma unroll
    for (int i = 0; i < 4; ++i)
#pragma unroll
      for (int j = 0; j < 4; ++j)
        acc[i][j] = __builtin_amdgcn_mfma_f32_16x16x32_bf16(afA[i], bfvA[j], acc[i][j], 0, 0, 0);
    __builtin_amdgcn_s_setprio(0);

    // ---- phase 1: MFMA(afB,bfvA); prefetch afA=(mh0,ks1), bfvB=(ks1); stage B x4 ----
    ldAfrag(afA, cA, 0, 1);
    ldBfrag(bfvB, cB, 1);
    if (st) { stageB(0, kn, bnx); stageB(1, kn, bnx); stageB(2, kn, bnx); stageB(3, kn, bnx); }
    __builtin_amdgcn_s_setprio(1);
#pragma unroll
    for (int i = 0; i < 4; ++i)
#pragma unroll
      for (int j = 0; j < 4; ++j)
        acc[4 + i][j] = __builtin_amdgcn_mfma_f32_16x16x32_bf16(afB[i], bfvA[j], acc[4 + i][j], 0, 0, 0);
    __builtin_amdgcn_s_setprio(0);

    // ---- phase 2: MFMA(afA,bfvB); prefetch afB=(mh1,ks1) ----
    ldAfrag(afB, cA, 1, 1);
    __builtin_amdgcn_s_setprio(1);
#pragma unroll
    for (int i = 0; i < 4; ++i)
#pragma unroll
      for (int j = 0; j < 4; ++j)
        acc[i][j] = __builtin_amdgcn_mfma_f32_16x16x32_bf16(afA[i], bfvB[j], acc[i][j], 0, 0, 0);
    __builtin_amdgcn_s_setprio(0);

    // ---- phase 3: MFMA(afB,bfvB); single per-tile drain + barrier ----
    __builtin_amdgcn_s_setprio(1);
#pragma unroll
    for (int i = 0; i < 4; ++i)
#pragma unroll
      for (int j = 0; j < 4; ++j)
        acc[4 + i][j] = __builtin_amdgcn_mfma_f32_16x16x32_bf16(afB[i], bfvB[j], acc[4 + i][j], 0, 0, 0);
    __builtin_amdgcn_s_setprio(0);
    TBAR;
    if (st) {  // first fragments of next tile from the freshly-drained buffer
      ldAfrag(afA, lds + bnx * 32768, 0, 0);
      ldBfrag(bfvA, lds + 65536 + bnx * 32768, 0);
    }
  }

  // ---- epilogue: stage tile in LDS, then wide (rope-fused) stores ----
  __syncthreads();
  const bool trstage = (EPI == 5) && (n0 >= 2048);
  if (trstage) {
#pragma unroll
    for (int i = 0; i < 8; ++i)
#pragma unroll
      for (int j = 0; j < 4; ++j) {
        int col = (wn << 6) + (j << 4) + lr;
#pragma unroll
        for (int r = 0; r < 4; ++r) {
          int row = (wm << 7) + (i << 4) + (g << 2) + r;
          *(ushort*)(lds + (col << 9) + ((row << 1) ^ ((col & 7) << 4))) = f2bf(acc[i][j][r]);
        }
      }
  } else {
#pragma unroll
    for (int i = 0; i < 8; ++i)
#pragma unroll
      for (int j = 0; j < 4; ++j) {
        int col = (wn << 6) + (j << 4) + lr;
#pragma unroll
        for (int r = 0; r < 4; ++r) {
          int row = (wm << 7) + (i << 4) + (g << 2) + r;
          *(ushort*)(lds + (row << 9) + ((col << 1) ^ ((row & 7) << 4))) = f2bf(acc[i][j][r]);
        }
      }
  }
  __syncthreads();

  if (EPI == 1) {
    ushort* C = (ushort*)Cout;
#pragma unroll
    for (int it = 0; it < 16; ++it) {
      int idx = it * 512 + t;
      int row = idx >> 5, ch = idx & 31;
      uint4 v = *(const uint4*)(lds + (row << 9) + ((ch << 4) ^ ((row & 7) << 4)));
      uint4 p = *(const uint4*)(lds + (row << 9) + (((ch ^ 16) << 4) ^ ((row & 7) << 4)));
      int pos = (m0 + row) & (NS - 1);
      int d0 = ch << 3;
      float4 c0 = *(const float4*)(cosT + (size_t)pos * 256 + d0);
      float4 c1 = *(const float4*)(cosT + (size_t)pos * 256 + d0 + 4);
      float4 s0 = *(const float4*)(sinT + (size_t)pos * 256 + d0);
      float4 s1 = *(const float4*)(sinT + (size_t)pos * 256 + d0 + 4);
      float cs[8] = {c0.x, c0.y, c0.z, c0.w, c1.x, c1.y, c1.z, c1.w};
      float ss[8] = {s0.x, s0.y, s0.z, s0.w, s1.x, s1.y, s1.z, s1.w};
      const float sgn = (ch < 16) ? -1.f : 1.f;
      const ushort* vv = (const ushort*)&v;
      const ushort* pp = (const ushort*)&p;
      ushort o[8];
#pragma unroll
      for (int e = 0; e < 8; ++e)
        o[e] = f2bf(bf2f(vv[e]) * cs[e] + sgn * bf2f(pp[e]) * ss[e]);
      *(uint4*)(C + (size_t)(m0 + row) * N + n0 + (ch << 3)) = *(const uint4*)o;
    }
  } else if (EPI == 5) {
    ushort* C = (ushort*)Cout;
    if (n0 < 2048) {  // K half -> kbuf, WITH RoPE
#pragma unroll
      for (int it = 0; it < 16; ++it) {
        int idx = it * 512 + t;
        int row = idx >> 5, ch = idx & 31;
        uint4 v = *(const uint4*)(lds + (row << 9) + ((ch << 4) ^ ((row & 7) << 4)));
        uint4 p = *(const uint4*)(lds + (row << 9) + (((ch ^ 16) << 4) ^ ((row & 7) << 4)));
        int pos = (m0 + row) & (NS - 1);
        int d0 = ch << 3;
        float4 c0 = *(const float4*)(cosT + (size_t)pos * 256 + d0);
        float4 c1 = *(const float4*)(cosT + (size_t)pos * 256 + d0 + 4);
        float4 s0 = *(const float4*)(sinT + (size_t)pos * 256 + d0);
        float4 s1 = *(const float4*)(sinT + (size_t)pos * 256 + d0 + 4);
        float cs[8] = {c0.x, c0.y, c0.z, c0.w, c1.x, c1.y, c1.z, c1.w};
        float ss[8] = {s0.x, s0.y, s0.z, s0.w, s1.x, s1.y, s1.z, s1.w};
        const float sgn = (ch < 16) ? -1.f : 1.f;
        const ushort* vv = (const ushort*)&v;
        const ushort* pp = (const ushort*)&p;
        ushort o[8];
#pragma unroll
        for (int e = 0; e < 8; ++e)
          o[e] = f2bf(bf2f(vv[e]) * cs[e] + sgn * bf2f(pp[e]) * ss[e]);
        *(uint4*)(C + (size_t)(m0 + row) * 2048 + n0 + (ch << 3)) = *(const uint4*)o;
      }
    } else {
      // V half -> tiled vtbuf (no rope). Fully linear store: elem = base + s*8.
      ushort* vC = C + (size_t)4096 * 2048;
      const int plane = (m0 >> 11) * NKVH + ((n0 - 2048) >> 8);
      ushort* dst = vC + (size_t)plane * ((size_t)NS * DH) + (size_t)((m0 & (NS - 1)) >> 5) * 8192;
#pragma unroll
      for (int it = 0; it < 16; ++it) {
        int s = it * 512 + t;
        int lr2 = s & 7, kq = (s >> 3) & 7, dt_l = (s >> 6) & 15, sb_l = s >> 10;
        int d0 = (dt_l << 4) + (lr2 << 1);   // lds col
        int r0 = (sb_l << 5) + (kq << 2);    // lds row (token)
        uint2 a = *(const uint2*)(lds + (d0 << 9) + ((r0 << 1) ^ ((d0 & 7) << 4)));
        uint2 b2 = *(const uint2*)(lds + ((d0 + 1) << 9) + ((r0 << 1) ^ (((d0 + 1) & 7) << 4)));
        uint4 v; v.x = a.x; v.y = a.y; v.z = b2.x; v.w = b2.y;
        *(uint4*)(dst + (size_t)s * 8) = v;
      }
    }
  } else {
    float* Cf = (float*)Cout;
#pragma unroll
    for (int it = 0; it < 32; ++it) {
      int idx = it * 512 + t;
      int row = idx >> 6, qd = idx & 63;
      ushort4 hv = *(const ushort4*)(lds + (row << 9) + ((qd << 3) ^ ((row & 7) << 4)));
      float4 fv;
      fv.x = bf2f(hv.x); fv.y = bf2f(hv.y); fv.z = bf2f(hv.z); fv.w = bf2f(hv.w);
      *(float4*)(Cf + (size_t)(m0 + row) * N + n0 + (qd << 2)) = fv;
    }
  }
}

// ---------------- flash attention v6.2: v6.1 + split QK chain --------------
// grid 1024. xcd=bid&7 -> planes {2x,2x+1}; heavy q-blocks first (LPT).
// Tiled-V (linear gload16, bank-bijective PV reads). exp2 softcap softmax.
// QK uses TWO independent MFMA accumulators (even/odd ks) to halve the
// dependent-chain latency; merged with 4 adds.
__global__ __launch_bounds__(256) void attn_kernel(const ushort* __restrict__ q,
                                                   const ushort* __restrict__ k,
                                                   const ushort* __restrict__ vt,
                                                   ushort* __restrict__ ao) {
  __shared__ alignas(16) char lK[2][16384];
  __shared__ alignas(16) char lV[2][16384];
  const int bid = (int)blockIdx.x;
  const int x = bid & 7;
  const int s_ = bid >> 3;       // 0..127
  const int rnd = s_ >> 5;       // 0..3
  const int c = s_ & 31;
  const int a = c >> 1;
  const int hl = c & 1;
  const int plane = (x << 1) | (rnd & 1);
  int qb;
  if (rnd < 2) qb = 16 + a;          // heavy first (LPT)
  else if (rnd == 2) qb = a;         // light ascending
  else qb = 15 - a;                  // light descending
  const int b = plane >> 3;
  const int kvh = plane & 7;
  const int h = (kvh << 1) | hl;
  const int qb0 = qb << 6;
  const int t = threadIdx.x;
  const int lane = t & 63;
  const int w = t >> 6;
  const int g = lane >> 4;
  const int lr = lane & 15;

  const int qrow = qb0 + (w << 4) + lr;
  bf16x8_t qf[8];
  const ushort* qbase = q + (size_t)(b * NS + qrow) * (NHEADS * DH) + h * DH;
#pragma unroll
  for (int ks = 0; ks < 8; ++ks)
    qf[ks] = *(const bf16x8_t*)(qbase + (ks << 5) + (g << 3));

  float l_r = 0.f;
  f32x4_t oacc[16] = {};

  const int qminw = qb0 + (w << 4);
  const int qmaxw = qminw + 15;
  int t_lo = qb0 - (WIN - 1);
  if (t_lo < 0) t_lo = 0;
  t_lo &= ~31;
  const int t_hi = qb0 + 63;
  const int nt = ((t_hi - t_lo) >> 5) + 1;

  const ushort* kgb = k + (size_t)(b * NS) * (NKVH * DH) + kvh * DH;
  const ushort* vgb = vt + (size_t)(b * NKVH + kvh) * ((size_t)NS * DH);  // tiled plane

  auto stage = [&](int kt, int bi) {
    char* dk = lK[bi];
    char* dv = lV[bi];
    const int sb = kt >> 5;
#pragma unroll
    for (int j = 0; j < 4; ++j) {
      int i = (w << 2) + j;  // 0..15
      int row = (i << 1) + (lane >> 5);
      int ck = (lane & 31) ^ (row & 7);
      gload16(kgb + (size_t)(kt + row) * (NKVH * DH) + (ck << 3), dk + (i << 10));
      gload16(vgb + (size_t)sb * 8192 + (((i << 6) + lane) << 3), dv + (i << 10));
    }
  };

  int cur = 0;
  stage(t_lo, 0);
  __syncthreads();

  for (int i = 0; i < nt; ++i) {
    const int kt = t_lo + (i << 5);
    if (i + 1 < nt) stage(kt + 32, cur ^ 1);  // async prefetch into other buf
    const char* lk = lK[cur];
    const char* lv = lV[cur];
#pragma unroll
    for (int sub = 0; sub < 2; ++sub) {
      const int key0 = kt + (sub << 4);
      if (key0 > qmaxw) continue;
      if (key0 + 15 < qminw - (WIN - 1)) continue;

      f32x4_t sa = {}, sb2 = {};
      __builtin_amdgcn_s_setprio(1);
#pragma unroll
      for (int ks = 0; ks < 8; ks += 2) {
        int row = (sub << 4) + lr;
        bf16x8_t kf0 = *(const bf16x8_t*)(lk + (((row << 9) + (ks << 6) + (g << 4)) ^ ((row & 7) << 4)));
        bf16x8_t kf1 = *(const bf16x8_t*)(lk + (((row << 9) + ((ks + 1) << 6) + (g << 4)) ^ ((row & 7) << 4)));
        sa  = __builtin_amdgcn_mfma_f32_16x16x32_bf16(kf0, qf[ks], sa, 0, 0, 0);
        sb2 = __builtin_amdgcn_mfma_f32_16x16x32_bf16(kf1, qf[ks + 1], sb2, 0, 0, 0);
      }
      __builtin_amdgcn_s_setprio(0);
      f32x4_t sacc;
#pragma unroll
      for (int r = 0; r < 4; ++r) sacc[r] = sa[r] + sb2[r];

      float pvv[4];
      const bool full = (key0 + 15 <= qminw) && (key0 >= qmaxw - (WIN - 1));
      if (full) {
#pragma unroll
        for (int r = 0; r < 4; ++r) { pvv[r] = pexp(sacc[r]); l_r += pvv[r]; }
      } else {
#pragma unroll
        for (int r = 0; r < 4; ++r) {
          int key = key0 + (g << 2) + r;
          bool ok = (key <= qrow) && (qrow - key < WIN);
          pvv[r] = ok ? pexp(sacc[r]) : 0.f;
          l_r += pvv[r];
        }
      }

      s16x4_t pa;  // truncating f32->bf16 (bias <=0.4%, inside threshold)
      pa[0] = (short)(ushort)(__builtin_bit_cast(unsigned, pvv[0]) >> 16);
      pa[1] = (short)(ushort)(__builtin_bit_cast(unsigned, pvv[1]) >> 16);
      pa[2] = (short)(ushort)(__builtin_bit_cast(unsigned, pvv[2]) >> 16);
      pa[3] = (short)(ushort)(__builtin_bit_cast(unsigned, pvv[3]) >> 16);

      const int kqoff = ((sub << 2) + g) << 7;  // kq*128 bytes
      __builtin_amdgcn_s_setprio(1);
#pragma unroll
      for (int dt = 0; dt < 16; ++dt) {
        s16x4_t vf = *(const s16x4_t*)(lv + (dt << 10) + kqoff + (lr << 3));
        oacc[dt] = mfma_pv(pa, vf, oacc[dt]);
      }
      __builtin_amdgcn_s_setprio(0);
    }
    __syncthreads();  // drains gloads (next tile ready) + all waves done with cur
    cur ^= 1;
  }

  l_r += __shfl_xor(l_r, 16);
  l_r += __shfl_xor(l_r, 32);
  float dn[4];
#pragma unroll
  for (int r = 0; r < 4; ++r)
    dn[r] = 1.0f / __shfl(l_r, (g << 2) + r);

  const int orow0 = b * NS + qb0 + (w << 4) + (g << 2);
#pragma unroll
  for (int dt = 0; dt < 16; ++dt) {
    int col = h * DH + (dt << 4) + lr;
#pragma unroll
    for (int r = 0; r < 4; ++r) {
      ao[(size_t)(orow0 + r) * (NHEADS * DH) + col] = f2bf(oacc[dt][r] * dn[r]);
    }
  }
}

extern "C" void kernel_launch(void* const* d_in, const int* in_sizes, int n_in,
                              void* d_out, int out_size, void* d_ws, size_t ws_size,
                              hipStream_t stream) {
  const float* hs   = (const float*)d_in[0];
  const float* sint = (const float*)d_in[3];
  const float* cost = (const float*)d_in[4];
  const float* Wq = (const float*)d_in[6];
  const float* Wk = (const float*)d_in[7];
  const float* Wv = (const float*)d_in[8];
  const float* Wo = (const float*)d_in[9];

  char* ws = (char*)d_ws;
  size_t off = 0;
  auto alloc = [&](size_t bytes) {
    char* p = ws + off;
    off += (bytes + 255) & ~(size_t)255;
    return p;
  };
  ushort* hsb   = (ushort*)alloc((size_t)4096 * 3584 * 2);  // hs in bf16
  ushort* wT    = (ushort*)alloc((size_t)4096 * 3584 * 2);  // reused weight^T buffer
  ushort* qbuf  = (ushort*)alloc((size_t)4096 * 4096 * 2);
  ushort* kbuf  = (ushort*)alloc((size_t)4096 * 2048 * 2);  // MUST precede vtbuf
  ushort* vtbuf = (ushort*)alloc((size_t)4096 * 2048 * 2);  // = kbuf + 4096*2048 (tiled)
  ushort* aobuf = qbuf;  // alias: attn writes exactly the region only it reads
  if (off > ws_size) return;

  // hs f32 -> bf16
  f32_to_bf16_kernel<<<(4096 * 3584 / 4) / 256, 256, 0, stream>>>(hs, hsb, 4096 * 3584 / 4);

  // fused K+V projection (RoPE fused on K half): Bt = [WkT; WvT] stacked in wT
  transpose_f32_bf16<<<(3584 / 64) * (2048 / 64), 256, 0, stream>>>(Wk, wT, 3584, 2048);
  transpose_f32_bf16<<<(3584 / 64) * (2048 / 64), 256, 0, stream>>>(Wv, wT + (size_t)2048 * 3584, 3584, 2048);
  gemm256<5><<<16 * 16, 512, 0, stream>>>(hsb, wT, kbuf, sint, cost, 4096, 4096, 3584);

  // Q projection (RoPE fused)
  transpose_f32_bf16<<<(3584 / 64) * (4096 / 64), 256, 0, stream>>>(Wq, wT, 3584, 4096);
  gemm256<1><<<16 * 16, 512, 0, stream>>>(hsb, wT, qbuf, sint, cost, 4096, 4096, 3584);

  // attention: QBLK=64, LPT/XCD decode (ao aliases qbuf)
  attn_kernel<<<NB * NHEADS * (NS / 64), 256, 0, stream>>>(qbuf, kbuf, vtbuf, aobuf);

  // output projection, f32 out
  transpose_f32_bf16<<<(4096 / 64) * (3584 / 64), 256, 0, stream>>>(Wo, wT, 4096, 3584);
  gemm256<2><<<16 * 14, 512, 0, stream>>>(aobuf, wT, d_out, nullptr, nullptr, 4096, 3584, 4096);
}

// Round 19
// 514.137 us; speedup vs baseline: 1.5859x; 1.0067x over previous
//
#include <hip/hip_runtime.h>
#include <hip/hip_bf16.h>

typedef __bf16 bf16x8_t __attribute__((ext_vector_type(8)));
typedef __bf16 bf16x4_t __attribute__((ext_vector_type(4)));
typedef short s16x4_t  __attribute__((ext_vector_type(4)));
typedef float f32x4_t  __attribute__((ext_vector_type(4)));

#define NB 2
#define NS 2048
#define NHID 3584
#define NHEADS 16
#define NKVH 8
#define DH 256
#define WIN 1024

__device__ __forceinline__ float bf2f(ushort u) {
  union { unsigned v; float f; } x; x.v = ((unsigned)u) << 16; return x.f;
}
__device__ __forceinline__ ushort f2bf(float f) {
  unsigned x = __builtin_bit_cast(unsigned, f);
  unsigned r = (x + 0x7fffu + ((x >> 16) & 1u)) >> 16;
  return (ushort)r;
}

__device__ __forceinline__ void gload16(const void* g, void* l) {
  __builtin_amdgcn_global_load_lds((const __attribute__((address_space(1))) void*)g,
                                   (__attribute__((address_space(3))) void*)l, 16, 0, 0);
}

__device__ __forceinline__ f32x4_t mfma_pv(s16x4_t a, s16x4_t b, f32x4_t c) {
#if __has_builtin(__builtin_amdgcn_mfma_f32_16x16x16_bf16)
  return __builtin_amdgcn_mfma_f32_16x16x16_bf16(
      __builtin_bit_cast(bf16x4_t, a), __builtin_bit_cast(bf16x4_t, b), c, 0, 0, 0);
#else
  return __builtin_amdgcn_mfma_f32_16x16x16bf16_1k(a, b, c, 0, 0, 0);
#endif
}

__device__ __forceinline__ float fexp2(float x) {
#if __has_builtin(__builtin_amdgcn_exp2f)
  return __builtin_amdgcn_exp2f(x);
#else
  return exp2f(x);
#endif
}
__device__ __forceinline__ float frcp(float x) {
#if __has_builtin(__builtin_amdgcn_rcpf)
  return __builtin_amdgcn_rcpf(x);
#else
  return 1.0f / x;
#endif
}

// softcap softmax weight, uniformly scaled by e^-25 (cancels in l-normalize):
// p' = exp(25 - 100/(e^{2x}+1)), x = s/800  ==> exp2 form, clamp-free
__device__ __forceinline__ float pexp(float s) {
  float e = fexp2(s * 0.0036067376f);
  float r = frcp(e + 1.0f);
  return fexp2(36.067376f - 144.2695041f * r);
}

// ---------------- f32 -> bf16 elementwise convert (x4 vectorized) ---------
__global__ __launch_bounds__(256) void f32_to_bf16_kernel(const float* __restrict__ in,
                                                          ushort* __restrict__ out, int n4) {
  int i = (int)blockIdx.x * 256 + (int)threadIdx.x;
  if (i < n4) {
    float4 v = ((const float4*)in)[i];
    ushort4 o;
    o.x = f2bf(v.x); o.y = f2bf(v.y); o.z = f2bf(v.z); o.w = f2bf(v.w);
    ((ushort4*)out)[i] = o;
  }
}

// ------------- transpose+convert: f32 in[R][C] -> bf16 out[C][R] ----------
// Vectorized: float4 global loads (1KB/wave), ushort4 LDS writes,
// uint4 global stores (8 contiguous out-elements per thread-iter).
__global__ __launch_bounds__(256) void transpose_f32_bf16(const float* __restrict__ in,
                                                          ushort* __restrict__ out,
                                                          int R, int Cc) {
  __shared__ ushort tile[64][72];
  const int t = threadIdx.x;
  const int ct = Cc >> 6;
  const int by = blockIdx.x / ct;
  const int bx = blockIdx.x % ct;
  const int r0 = by << 6, c0 = bx << 6;
#pragma unroll
  for (int i = 0; i < 4; ++i) {
    int v = i * 256 + t;            // 0..1023
    int r = v >> 4, c4 = (v & 15) << 2;
    float4 f = *(const float4*)(in + (size_t)(r0 + r) * Cc + c0 + c4);
    ushort4 o;
    o.x = f2bf(f.x); o.y = f2bf(f.y); o.z = f2bf(f.z); o.w = f2bf(f.w);
    *(ushort4*)&tile[r][c4] = o;    // 144B row stride -> 8B aligned
  }
  __syncthreads();
#pragma unroll
  for (int i = 0; i < 2; ++i) {
    int v = i * 256 + t;            // 0..511
    int rr = v >> 3;                // out-row (= in-col) 0..63
    int c8 = (v & 7) << 3;          // chunk of 8 in-rows
    ushort o[8];
#pragma unroll
    for (int e = 0; e < 8; ++e) o[e] = tile[c8 + e][rr];
    *(uint4*)(out + (size_t)(c0 + rr) * R + r0 + c8) = *(const uint4*)o;
  }
}

// ============ 256x256 GEMM, single-barrier K-loop =========================
// Stages write buf^1 while ds_reads target buf (disjoint); every ds_read dest
// is consumed by MFMA before TBAR, so lgkm retired block-wide at the single
// vmcnt(0)+s_barrier per K-tile. Fragment prefetch rotation gives each MFMA a
// full phase of ds-read slack via compiler-counted lgkm waits.
#define TBAR do { \
    asm volatile("s_waitcnt vmcnt(0)" ::: "memory"); \
    __builtin_amdgcn_sched_barrier(0); \
    __builtin_amdgcn_s_barrier(); } while (0)

// EPI=1: bf16 C[M][N] + fused RoPE. EPI=2: f32 C. EPI=5: fused KV — K half
// WITH RoPE -> kbuf; V half -> vtbuf ATTN-TILED: elem(b,kvh,s,d) =
//   plane*524288 + (s>>5)*8192 + (d>>4)*512 + ((s&31)>>2)*64 + (d&15)*4 + (s&3)
template <int EPI>
__global__ __launch_bounds__(512, 2) void gemm256(const ushort* __restrict__ A,
                                                  const ushort* __restrict__ Bt,
                                                  void* __restrict__ Cout,
                                                  const float* __restrict__ sinT,
                                                  const float* __restrict__ cosT,
                                                  int M, int N, int K) {
  __shared__ alignas(16) char lds[131072];
  const int t = threadIdx.x;
  const int lane = t & 63;
  const int wid = t >> 6;
  const int wm = wid >> 2;   // 0..1
  const int wn = wid & 3;    // 0..3
  const int g = lane >> 4;
  const int lr = lane & 15;
  const int lrow8 = lane >> 3;
  const int lp = (lane & 7) ^ lrow8;  // pre-swizzled staging chunk

  const int nbn = N >> 8;
  const int nwg = (int)gridDim.x;
  const int bid = (int)blockIdx.x;
  const int swz = (bid & 7) * (nwg >> 3) + (bid >> 3);
  const int bm = swz / nbn, bn = swz % nbn;
  const int m0 = bm << 8, n0 = bn << 8;

  f32x4_t acc[8][4] = {};
  const int T = K >> 6;

  auto stageA = [&](int q, int koff, int bufn) {
    int row = (q << 6) + (wid << 3) + lrow8;
    gload16(A + (size_t)(m0 + row) * K + koff + (lp << 3),
            lds + bufn * 32768 + (q << 13) + (wid << 10));
  };
  auto stageB = [&](int q, int koff, int bufn) {
    int row = (q << 6) + (wid << 3) + lrow8;
    gload16(Bt + (size_t)(n0 + row) * K + koff + (lp << 3),
            lds + 65536 + bufn * 32768 + (q << 13) + (wid << 10));
  };
  auto ldAfrag = [&](bf16x8_t* dst, const char* cA, int mh, int ks) {
#pragma unroll
    for (int i = 0; i < 4; ++i) {
      int row = (wm << 7) + (mh << 6) + (i << 4) + lr;
      dst[i] = *(const bf16x8_t*)(cA + (row << 7) + (((ks << 6) + (g << 4)) ^ ((row & 7) << 4)));
    }
  };
  auto ldBfrag = [&](bf16x8_t* dst, const char* cB, int ks) {
#pragma unroll
    for (int j = 0; j < 4; ++j) {
      int row = (wn << 6) + (j << 4) + lr;
      dst[j] = *(const bf16x8_t*)(cB + (row << 7) + (((ks << 6) + (g << 4)) ^ ((row & 7) << 4)));
    }
  };

  // prologue: tile 0 -> buf 0
#pragma unroll
  for (int q = 0; q < 4; ++q) { stageA(q, 0, 0); stageB(q, 0, 0); }
  asm volatile("s_waitcnt vmcnt(0)" ::: "memory");
  __builtin_amdgcn_s_barrier();

  bf16x8_t afA[4], afB[4], bfvA[4], bfvB[4];
  ldAfrag(afA, lds, 0, 0);
  ldBfrag(bfvA, lds + 65536, 0);

  for (int tt = 0; tt < T; ++tt) {
    const int bc = tt & 1;
    const int bnx = bc ^ 1;
    const bool st = (tt + 1 < T);
    const int kn = (tt + 1) << 6;
    const char* cA = lds + bc * 32768;
    const char* cB = lds + 65536 + bc * 32768;

    // ---- phase 0: MFMA(afA,bfvA); prefetch afB=(mh1,ks0); stage A x4 ----
    ldAfrag(afB, cA, 1, 0);
    if (st) { stageA(0, kn, bnx); stageA(1, kn, bnx); stageA(2, kn, bnx); stageA(3, kn, bnx); }
    __builtin_amdgcn_s_setprio(1);
#pragma unroll
    for (int i = 0; i < 4; ++i)
#pragma unroll
      for (int j = 0; j < 4; ++j)
        acc[i][j] = __builtin_amdgcn_mfma_f32_16x16x32_bf16(afA[i], bfvA[j], acc[i][j], 0, 0, 0);
    __builtin_amdgcn_s_setprio(0);

    // ---- phase 1: MFMA(afB,bfvA); prefetch afA=(mh0,ks1), bfvB=(ks1); stage B x4 ----
    ldAfrag(afA, cA, 0, 1);
    ldBfrag(bfvB, cB, 1);
    if (st) { stageB(0, kn, bnx); stageB(1, kn, bnx); stageB(2, kn, bnx); stageB(3, kn, bnx); }
    __builtin_amdgcn_s_setprio(1);
#pragma unroll
    for (int i = 0; i < 4; ++i)
#pragma unroll
      for (int j = 0; j < 4; ++j)
        acc[4 + i][j] = __builtin_amdgcn_mfma_f32_16x16x32_bf16(afB[i], bfvA[j], acc[4 + i][j], 0, 0, 0);
    __builtin_amdgcn_s_setprio(0);

    // ---- phase 2: MFMA(afA,bfvB); prefetch afB=(mh1,ks1) ----
    ldAfrag(afB, cA, 1, 1);
    __builtin_amdgcn_s_setprio(1);
#pragma unroll
    for (int i = 0; i < 4; ++i)
#pragma unroll
      for (int j = 0; j < 4; ++j)
        acc[i][j] = __builtin_amdgcn_mfma_f32_16x16x32_bf16(afA[i], bfvB[j], acc[i][j], 0, 0, 0);
    __builtin_amdgcn_s_setprio(0);

    // ---- phase 3: MFMA(afB,bfvB); single per-tile drain + barrier ----
    __builtin_amdgcn_s_setprio(1);
#pragma unroll
    for (int i = 0; i < 4; ++i)
#pragma unroll
      for (int j = 0; j < 4; ++j)
        acc[4 + i][j] = __builtin_amdgcn_mfma_f32_16x16x32_bf16(afB[i], bfvB[j], acc[4 + i][j], 0, 0, 0);
    __builtin_amdgcn_s_setprio(0);
    TBAR;
    if (st) {  // first fragments of next tile from the freshly-drained buffer
      ldAfrag(afA, lds + bnx * 32768, 0, 0);
      ldBfrag(bfvA, lds + 65536 + bnx * 32768, 0);
    }
  }

  // ---- epilogue: stage tile in LDS, then wide (rope-fused) stores ----
  __syncthreads();
  const bool trstage = (EPI == 5) && (n0 >= 2048);
  if (trstage) {
#pragma unroll
    for (int i = 0; i < 8; ++i)
#pragma unroll
      for (int j = 0; j < 4; ++j) {
        int col = (wn << 6) + (j << 4) + lr;
#pragma unroll
        for (int r = 0; r < 4; ++r) {
          int row = (wm << 7) + (i << 4) + (g << 2) + r;
          *(ushort*)(lds + (col << 9) + ((row << 1) ^ ((col & 7) << 4))) = f2bf(acc[i][j][r]);
        }
      }
  } else {
#pragma unroll
    for (int i = 0; i < 8; ++i)
#pragma unroll
      for (int j = 0; j < 4; ++j) {
        int col = (wn << 6) + (j << 4) + lr;
#pragma unroll
        for (int r = 0; r < 4; ++r) {
          int row = (wm << 7) + (i << 4) + (g << 2) + r;
          *(ushort*)(lds + (row << 9) + ((col << 1) ^ ((row & 7) << 4))) = f2bf(acc[i][j][r]);
        }
      }
  }
  __syncthreads();

  if (EPI == 1) {
    ushort* C = (ushort*)Cout;
#pragma unroll
    for (int it = 0; it < 16; ++it) {
      int idx = it * 512 + t;
      int row = idx >> 5, ch = idx & 31;
      uint4 v = *(const uint4*)(lds + (row << 9) + ((ch << 4) ^ ((row & 7) << 4)));
      uint4 p = *(const uint4*)(lds + (row << 9) + (((ch ^ 16) << 4) ^ ((row & 7) << 4)));
      int pos = (m0 + row) & (NS - 1);
      int d0 = ch << 3;
      float4 c0 = *(const float4*)(cosT + (size_t)pos * 256 + d0);
      float4 c1 = *(const float4*)(cosT + (size_t)pos * 256 + d0 + 4);
      float4 s0 = *(const float4*)(sinT + (size_t)pos * 256 + d0);
      float4 s1 = *(const float4*)(sinT + (size_t)pos * 256 + d0 + 4);
      float cs[8] = {c0.x, c0.y, c0.z, c0.w, c1.x, c1.y, c1.z, c1.w};
      float ss[8] = {s0.x, s0.y, s0.z, s0.w, s1.x, s1.y, s1.z, s1.w};
      const float sgn = (ch < 16) ? -1.f : 1.f;
      const ushort* vv = (const ushort*)&v;
      const ushort* pp = (const ushort*)&p;
      ushort o[8];
#pragma unroll
      for (int e = 0; e < 8; ++e)
        o[e] = f2bf(bf2f(vv[e]) * cs[e] + sgn * bf2f(pp[e]) * ss[e]);
      *(uint4*)(C + (size_t)(m0 + row) * N + n0 + (ch << 3)) = *(const uint4*)o;
    }
  } else if (EPI == 5) {
    ushort* C = (ushort*)Cout;
    if (n0 < 2048) {  // K half -> kbuf, WITH RoPE
#pragma unroll
      for (int it = 0; it < 16; ++it) {
        int idx = it * 512 + t;
        int row = idx >> 5, ch = idx & 31;
        uint4 v = *(const uint4*)(lds + (row << 9) + ((ch << 4) ^ ((row & 7) << 4)));
        uint4 p = *(const uint4*)(lds + (row << 9) + (((ch ^ 16) << 4) ^ ((row & 7) << 4)));
        int pos = (m0 + row) & (NS - 1);
        int d0 = ch << 3;
        float4 c0 = *(const float4*)(cosT + (size_t)pos * 256 + d0);
        float4 c1 = *(const float4*)(cosT + (size_t)pos * 256 + d0 + 4);
        float4 s0 = *(const float4*)(sinT + (size_t)pos * 256 + d0);
        float4 s1 = *(const float4*)(sinT + (size_t)pos * 256 + d0 + 4);
        float cs[8] = {c0.x, c0.y, c0.z, c0.w, c1.x, c1.y, c1.z, c1.w};
        float ss[8] = {s0.x, s0.y, s0.z, s0.w, s1.x, s1.y, s1.z, s1.w};
        const float sgn = (ch < 16) ? -1.f : 1.f;
        const ushort* vv = (const ushort*)&v;
        const ushort* pp = (const ushort*)&p;
        ushort o[8];
#pragma unroll
        for (int e = 0; e < 8; ++e)
          o[e] = f2bf(bf2f(vv[e]) * cs[e] + sgn * bf2f(pp[e]) * ss[e]);
        *(uint4*)(C + (size_t)(m0 + row) * 2048 + n0 + (ch << 3)) = *(const uint4*)o;
      }
    } else {
      // V half -> tiled vtbuf (no rope). Fully linear store: elem = base + s*8.
      ushort* vC = C + (size_t)4096 * 2048;
      const int plane = (m0 >> 11) * NKVH + ((n0 - 2048) >> 8);
      ushort* dst = vC + (size_t)plane * ((size_t)NS * DH) + (size_t)((m0 & (NS - 1)) >> 5) * 8192;
#pragma unroll
      for (int it = 0; it < 16; ++it) {
        int s = it * 512 + t;
        int lr2 = s & 7, kq = (s >> 3) & 7, dt_l = (s >> 6) & 15, sb_l = s >> 10;
        int d0 = (dt_l << 4) + (lr2 << 1);   // lds col
        int r0 = (sb_l << 5) + (kq << 2);    // lds row (token)
        uint2 a = *(const uint2*)(lds + (d0 << 9) + ((r0 << 1) ^ ((d0 & 7) << 4)));
        uint2 b2 = *(const uint2*)(lds + ((d0 + 1) << 9) + ((r0 << 1) ^ (((d0 + 1) & 7) << 4)));
        uint4 v; v.x = a.x; v.y = a.y; v.z = b2.x; v.w = b2.y;
        *(uint4*)(dst + (size_t)s * 8) = v;
      }
    }
  } else {
    float* Cf = (float*)Cout;
#pragma unroll
    for (int it = 0; it < 32; ++it) {
      int idx = it * 512 + t;
      int row = idx >> 6, qd = idx & 63;
      ushort4 hv = *(const ushort4*)(lds + (row << 9) + ((qd << 3) ^ ((row & 7) << 4)));
      float4 fv;
      fv.x = bf2f(hv.x); fv.y = bf2f(hv.y); fv.z = bf2f(hv.z); fv.w = bf2f(hv.w);
      *(float4*)(Cf + (size_t)(m0 + row) * N + n0 + (qd << 2)) = fv;
    }
  }
}

// ---------------- flash attention v6.1 (best measured: 147us) --------------
// grid 1024. xcd=bid&7 -> planes {2x,2x+1}; heavy q-blocks first (LPT).
// Tiled-V (linear gload16, bank-bijective PV reads). exp2 softcap softmax.
__global__ __launch_bounds__(256) void attn_kernel(const ushort* __restrict__ q,
                                                   const ushort* __restrict__ k,
                                                   const ushort* __restrict__ vt,
                                                   ushort* __restrict__ ao) {
  __shared__ alignas(16) char lK[2][16384];
  __shared__ alignas(16) char lV[2][16384];
  const int bid = (int)blockIdx.x;
  const int x = bid & 7;
  const int s_ = bid >> 3;       // 0..127
  const int rnd = s_ >> 5;       // 0..3
  const int c = s_ & 31;
  const int a = c >> 1;
  const int hl = c & 1;
  const int plane = (x << 1) | (rnd & 1);
  int qb;
  if (rnd < 2) qb = 16 + a;          // heavy first (LPT)
  else if (rnd == 2) qb = a;         // light ascending
  else qb = 15 - a;                  // light descending
  const int b = plane >> 3;
  const int kvh = plane & 7;
  const int h = (kvh << 1) | hl;
  const int qb0 = qb << 6;
  const int t = threadIdx.x;
  const int lane = t & 63;
  const int w = t >> 6;
  const int g = lane >> 4;
  const int lr = lane & 15;

  const int qrow = qb0 + (w << 4) + lr;
  bf16x8_t qf[8];
  const ushort* qbase = q + (size_t)(b * NS + qrow) * (NHEADS * DH) + h * DH;
#pragma unroll
  for (int ks = 0; ks < 8; ++ks)
    qf[ks] = *(const bf16x8_t*)(qbase + (ks << 5) + (g << 3));

  float l_r = 0.f;
  f32x4_t oacc[16] = {};

  const int qminw = qb0 + (w << 4);
  const int qmaxw = qminw + 15;
  int t_lo = qb0 - (WIN - 1);
  if (t_lo < 0) t_lo = 0;
  t_lo &= ~31;
  const int t_hi = qb0 + 63;
  const int nt = ((t_hi - t_lo) >> 5) + 1;

  const ushort* kgb = k + (size_t)(b * NS) * (NKVH * DH) + kvh * DH;
  const ushort* vgb = vt + (size_t)(b * NKVH + kvh) * ((size_t)NS * DH);  // tiled plane

  auto stage = [&](int kt, int bi) {
    char* dk = lK[bi];
    char* dv = lV[bi];
    const int sb = kt >> 5;
#pragma unroll
    for (int j = 0; j < 4; ++j) {
      int i = (w << 2) + j;  // 0..15
      int row = (i << 1) + (lane >> 5);
      int ck = (lane & 31) ^ (row & 7);
      gload16(kgb + (size_t)(kt + row) * (NKVH * DH) + (ck << 3), dk + (i << 10));
      gload16(vgb + (size_t)sb * 8192 + (((i << 6) + lane) << 3), dv + (i << 10));
    }
  };

  int cur = 0;
  stage(t_lo, 0);
  __syncthreads();

  for (int i = 0; i < nt; ++i) {
    const int kt = t_lo + (i << 5);
    if (i + 1 < nt) stage(kt + 32, cur ^ 1);  // async prefetch into other buf
    const char* lk = lK[cur];
    const char* lv = lV[cur];
#pragma unroll
    for (int sub = 0; sub < 2; ++sub) {
      const int key0 = kt + (sub << 4);
      if (key0 > qmaxw) continue;
      if (key0 + 15 < qminw - (WIN - 1)) continue;

      f32x4_t sacc = {};
      __builtin_amdgcn_s_setprio(1);
#pragma unroll
      for (int ks = 0; ks < 8; ++ks) {
        int row = (sub << 4) + lr;
        bf16x8_t kf = *(const bf16x8_t*)(lk + (((row << 9) + (ks << 6) + (g << 4)) ^ ((row & 7) << 4)));
        sacc = __builtin_amdgcn_mfma_f32_16x16x32_bf16(kf, qf[ks], sacc, 0, 0, 0);
      }
      __builtin_amdgcn_s_setprio(0);

      float pvv[4];
      const bool full = (key0 + 15 <= qminw) && (key0 >= qmaxw - (WIN - 1));
      if (full) {
#pragma unroll
        for (int r = 0; r < 4; ++r) { pvv[r] = pexp(sacc[r]); l_r += pvv[r]; }
      } else {
#pragma unroll
        for (int r = 0; r < 4; ++r) {
          int key = key0 + (g << 2) + r;
          bool ok = (key <= qrow) && (qrow - key < WIN);
          pvv[r] = ok ? pexp(sacc[r]) : 0.f;
          l_r += pvv[r];
        }
      }

      s16x4_t pa;  // truncating f32->bf16 (bias <=0.4%, inside threshold)
      pa[0] = (short)(ushort)(__builtin_bit_cast(unsigned, pvv[0]) >> 16);
      pa[1] = (short)(ushort)(__builtin_bit_cast(unsigned, pvv[1]) >> 16);
      pa[2] = (short)(ushort)(__builtin_bit_cast(unsigned, pvv[2]) >> 16);
      pa[3] = (short)(ushort)(__builtin_bit_cast(unsigned, pvv[3]) >> 16);

      const int kqoff = ((sub << 2) + g) << 7;  // kq*128 bytes
      __builtin_amdgcn_s_setprio(1);
#pragma unroll
      for (int dt = 0; dt < 16; ++dt) {
        s16x4_t vf = *(const s16x4_t*)(lv + (dt << 10) + kqoff + (lr << 3));
        oacc[dt] = mfma_pv(pa, vf, oacc[dt]);
      }
      __builtin_amdgcn_s_setprio(0);
    }
    __syncthreads();  // drains gloads (next tile ready) + all waves done with cur
    cur ^= 1;
  }

  l_r += __shfl_xor(l_r, 16);
  l_r += __shfl_xor(l_r, 32);
  float dn[4];
#pragma unroll
  for (int r = 0; r < 4; ++r)
    dn[r] = 1.0f / __shfl(l_r, (g << 2) + r);

  const int orow0 = b * NS + qb0 + (w << 4) + (g << 2);
#pragma unroll
  for (int dt = 0; dt < 16; ++dt) {
    int col = h * DH + (dt << 4) + lr;
#pragma unroll
    for (int r = 0; r < 4; ++r) {
      ao[(size_t)(orow0 + r) * (NHEADS * DH) + col] = f2bf(oacc[dt][r] * dn[r]);
    }
  }
}

extern "C" void kernel_launch(void* const* d_in, const int* in_sizes, int n_in,
                              void* d_out, int out_size, void* d_ws, size_t ws_size,
                              hipStream_t stream) {
  const float* hs   = (const float*)d_in[0];
  const float* sint = (const float*)d_in[3];
  const float* cost = (const float*)d_in[4];
  const float* Wq = (const float*)d_in[6];
  const float* Wk = (const float*)d_in[7];
  const float* Wv = (const float*)d_in[8];
  const float* Wo = (const float*)d_in[9];

  char* ws = (char*)d_ws;
  size_t off = 0;
  auto alloc = [&](size_t bytes) {
    char* p = ws + off;
    off += (bytes + 255) & ~(size_t)255;
    return p;
  };
  ushort* hsb   = (ushort*)alloc((size_t)4096 * 3584 * 2);  // hs in bf16
  ushort* wT    = (ushort*)alloc((size_t)4096 * 3584 * 2);  // reused weight^T buffer
  ushort* qbuf  = (ushort*)alloc((size_t)4096 * 4096 * 2);
  ushort* kbuf  = (ushort*)alloc((size_t)4096 * 2048 * 2);  // MUST precede vtbuf
  ushort* vtbuf = (ushort*)alloc((size_t)4096 * 2048 * 2);  // = kbuf + 4096*2048 (tiled)
  ushort* aobuf = qbuf;  // alias: attn writes exactly the region only it reads
  if (off > ws_size) return;

  // hs f32 -> bf16
  f32_to_bf16_kernel<<<(4096 * 3584 / 4) / 256, 256, 0, stream>>>(hs, hsb, 4096 * 3584 / 4);

  // fused K+V projection (RoPE fused on K half): Bt = [WkT; WvT] stacked in wT
  transpose_f32_bf16<<<(3584 / 64) * (2048 / 64), 256, 0, stream>>>(Wk, wT, 3584, 2048);
  transpose_f32_bf16<<<(3584 / 64) * (2048 / 64), 256, 0, stream>>>(Wv, wT + (size_t)2048 * 3584, 3584, 2048);
  gemm256<5><<<16 * 16, 512, 0, stream>>>(hsb, wT, kbuf, sint, cost, 4096, 4096, 3584);

  // Q projection (RoPE fused)
  transpose_f32_bf16<<<(3584 / 64) * (4096 / 64), 256, 0, stream>>>(Wq, wT, 3584, 4096);
  gemm256<1><<<16 * 16, 512, 0, stream>>>(hsb, wT, qbuf, sint, cost, 4096, 4096, 3584);

  // attention: QBLK=64, LPT/XCD decode (ao aliases qbuf)
  attn_kernel<<<NB * NHEADS * (NS / 64), 256, 0, stream>>>(qbuf, kbuf, vtbuf, aobuf);

  // output projection, f32 out
  transpose_f32_bf16<<<(4096 / 64) * (3584 / 64), 256, 0, stream>>>(Wo, wT, 4096, 3584);
  gemm256<2><<<16 * 14, 512, 0, stream>>>(aobuf, wT, d_out, nullptr, nullptr, 4096, 3584, 4096);
}